// Round 1
// baseline (1333.190 us; speedup 1.0000x reference)
//
#include <hip/hip_runtime.h>
#include <hip/hip_bf16.h>

#define B_      16
#define N_TOK   1024
#define DIM_    768
#define HEADS_  12
#define DHEAD   64
#define KRES_   9

#define QKV_E   (12582912)           // B*HEADS*N*DHEAD
#define ROWS_   (B_*HEADS_*N_TOK)    // 196608
#define NBLK2   (ROWS_/4)            // 49152

typedef __attribute__((ext_vector_type(8))) short bf16x8;
typedef __attribute__((ext_vector_type(4))) float f32x4;

__device__ inline short f2b(float f) {
  unsigned u = __builtin_bit_cast(unsigned, f);
  u += 0x7fff + ((u >> 16) & 1);   // round-to-nearest-even
  return (short)(u >> 16);
}
__device__ inline float b2f(short s) {
  unsigned u = ((unsigned)(unsigned short)s) << 16;
  return __builtin_bit_cast(float, u);
}

// ---------------------------------------------------------------------------
// Generic bf16-MFMA GEMM: C[M,N] = A[M,K] * B[K,N]
// 64x64 tile per 256-thread block (4 waves, each wave: 16 rows x 64 cols).
// LDS: A tile [64][32] bf16, B tile stored transposed [64 n][32 k] bf16.
// MODE 0: scatter-write bf16 into q/k/v [B,h,N,d] buffers (QKV gemm, N=2304)
// MODE 1: write f32 + bias to out (projection gemm, N=768)
// ---------------------------------------------------------------------------
template<int MODE, bool ABF16>
__global__ __launch_bounds__(256) void gemm_mfma(
    const void* __restrict__ Araw, const float* __restrict__ Bmat,
    int N, int K,
    short* __restrict__ qkv_out, float* __restrict__ proj_out,
    const float* __restrict__ bias)
{
  __shared__ short As[64 * 40];
  __shared__ short Bs[64 * 40];

  const int tid  = threadIdx.x;
  const int lane = tid & 63;
  const int wid  = tid >> 6;
  const int rowBase = blockIdx.y << 6;
  const int colBase = blockIdx.x << 6;

  const int sr  = tid >> 2;          // staging row / col-of-B: 0..63
  const int skg = (tid & 3) << 3;    // staging k offset: 0,8,16,24

  const int fr  = lane & 15;         // fragment row (A) / col (B)
  const int fko = (lane >> 4) << 3;  // fragment k offset

  const float* Af = (const float*)Araw;
  const short* Ab = (const short*)Araw;

  f32x4 acc[4];
#pragma unroll
  for (int i = 0; i < 4; ++i) acc[i] = f32x4{0.f, 0.f, 0.f, 0.f};

  for (int k0 = 0; k0 < K; k0 += 32) {
    __syncthreads();
    // ---- stage A tile (convert f32->bf16 if needed) ----
    bf16x8 av;
    if (ABF16) {
      av = *(const bf16x8*)(Ab + (size_t)(rowBase + sr) * K + k0 + skg);
    } else {
      const float* ap = Af + (size_t)(rowBase + sr) * K + k0 + skg;
      float4 a0 = *(const float4*)ap;
      float4 a1 = *(const float4*)(ap + 4);
      av[0]=f2b(a0.x); av[1]=f2b(a0.y); av[2]=f2b(a0.z); av[3]=f2b(a0.w);
      av[4]=f2b(a1.x); av[5]=f2b(a1.y); av[6]=f2b(a1.z); av[7]=f2b(a1.w);
    }
    *(bf16x8*)(As + sr * 40 + skg) = av;
    // ---- stage B tile transposed: Bs[n][k] ----
    {
      const float* bp = Bmat + (size_t)(k0 + skg) * N + colBase + sr;
      bf16x8 bv;
#pragma unroll
      for (int j = 0; j < 8; ++j) bv[j] = f2b(bp[(size_t)j * N]);
      *(bf16x8*)(Bs + sr * 40 + skg) = bv;
    }
    __syncthreads();
    // ---- MFMA ----
    bf16x8 af = *(const bf16x8*)(As + (wid * 16 + fr) * 40 + fko);
#pragma unroll
    for (int nt = 0; nt < 4; ++nt) {
      bf16x8 bfr = *(const bf16x8*)(Bs + (nt * 16 + fr) * 40 + fko);
      acc[nt] = __builtin_amdgcn_mfma_f32_16x16x32_bf16(af, bfr, acc[nt], 0, 0, 0);
    }
  }

  // ---- epilogue: D layout col = lane&15, row = (lane>>4)*4 + e ----
#pragma unroll
  for (int nt = 0; nt < 4; ++nt) {
#pragma unroll
    for (int e = 0; e < 4; ++e) {
      int gr = rowBase + wid * 16 + ((lane >> 4) << 2) + e;
      int gc = colBase + nt * 16 + fr;
      float val = acc[nt][e];
      if (MODE == 0) {
        int part = gc / 768;
        int hd   = (gc % 768) / 64;
        int dd   = gc & 63;
        int b    = gr >> 10;
        int n    = gr & 1023;
        size_t idx = (size_t)part * QKV_E
                   + ((size_t)((b * 12 + hd) * 1024 + n) << 6) + dd;
        qkv_out[idx] = f2b(val);
      } else {
        proj_out[(size_t)gr * N + gc] = val + bias[gc];
      }
    }
  }
}

// ---------------------------------------------------------------------------
// Normalize q,k rows (64 elems) in place; emit per-block sums of normalized
// values for the global means. One wave per (b,h,n) row; 4 rows per block.
// ---------------------------------------------------------------------------
__global__ __launch_bounds__(256) void norm_mean_kernel(
    short* __restrict__ q, short* __restrict__ k, float* __restrict__ partials)
{
  int wid = threadIdx.x >> 6, lane = threadIdx.x & 63;
  int row = blockIdx.x * 4 + wid;
  size_t base = ((size_t)row << 6) + lane;
  float qv = b2f(q[base]), kv = b2f(k[base]);
  float qss = qv * qv, kss = kv * kv;
#pragma unroll
  for (int o = 32; o; o >>= 1) { qss += __shfl_xor(qss, o); kss += __shfl_xor(kss, o); }
  float qn = qv * rsqrtf(qss), kn = kv * rsqrtf(kss);
  q[base] = f2b(qn); k[base] = f2b(kn);
  float qs = qn, ks = kn;
#pragma unroll
  for (int o = 32; o; o >>= 1) { qs += __shfl_xor(qs, o); ks += __shfl_xor(ks, o); }
  __shared__ float sq[4], sk[4];
  if (lane == 0) { sq[wid] = qs; sk[wid] = ks; }
  __syncthreads();
  if (threadIdx.x == 0) {
    partials[blockIdx.x]         = sq[0] + sq[1] + sq[2] + sq[3];
    partials[NBLK2 + blockIdx.x] = sk[0] + sk[1] + sk[2] + sk[3];
  }
}

__global__ __launch_bounds__(256) void mean_reduce_kernel(
    const float* __restrict__ partials, float* __restrict__ means)
{
  float sq = 0.f, sk = 0.f;
  for (int i = threadIdx.x; i < NBLK2; i += 256) {
    sq += partials[i]; sk += partials[NBLK2 + i];
  }
#pragma unroll
  for (int o = 32; o; o >>= 1) { sq += __shfl_xor(sq, o); sk += __shfl_xor(sk, o); }
  __shared__ float s[8];
  int wid = threadIdx.x >> 6, lane = threadIdx.x & 63;
  if (lane == 0) { s[wid] = sq; s[4 + wid] = sk; }
  __syncthreads();
  if (threadIdx.x == 0) {
    means[0] = (s[0] + s[1] + s[2] + s[3]) / 12582912.f;
    means[1] = (s[4] + s[5] + s[6] + s[7]) / 12582912.f;
  }
}

// ---------------------------------------------------------------------------
// attn[bh][d][e] = sum_n 1[k_norm[bh,n,d] > mean_k] * v[bh,n,e]
// One block per (b,h). Thread owns (dd = tid/4, 16 e-values).
// ---------------------------------------------------------------------------
__global__ __launch_bounds__(256) void attn_kernel(
    const short* __restrict__ k, const short* __restrict__ v,
    const float* __restrict__ means, float* __restrict__ attn)
{
  int bh = blockIdx.x;
  int dd = threadIdx.x >> 2;
  int e0 = (threadIdx.x & 3) << 4;
  float mk = means[1];
  float acc[16];
#pragma unroll
  for (int i = 0; i < 16; ++i) acc[i] = 0.f;
  const short* kb = k + ((size_t)bh << 16);
  const short* vb = v + ((size_t)bh << 16);
  for (int n = 0; n < N_TOK; ++n) {
    bool on = (b2f(kb[(n << 6) + dd]) - mk) > 0.f;
    if (on) {
      const short* vp = vb + (n << 6) + e0;
      bf16x8 v0 = *(const bf16x8*)(vp);
      bf16x8 v1 = *(const bf16x8*)(vp + 8);
#pragma unroll
      for (int i = 0; i < 8; ++i) { acc[i] += b2f(v0[i]); acc[8 + i] += b2f(v1[i]); }
    }
  }
  float* ap = attn + ((size_t)bh << 12) + dd * 64 + e0;
#pragma unroll
  for (int i = 0; i < 16; ++i) ap[i] = acc[i];
}

// ---------------------------------------------------------------------------
// out row: o = 0.5 v + (1/pi) * qbits . attn ; normalize ; + depthwise conv ;
// write bf16 into mid[B,N,768]. One wave per (b,h,n) row.
// ---------------------------------------------------------------------------
__global__ __launch_bounds__(256) void out_kernel(
    const short* __restrict__ q, const short* __restrict__ v,
    const float* __restrict__ attn, const float* __restrict__ means,
    const float* __restrict__ wd, short* __restrict__ mid)
{
  int wid = threadIdx.x >> 6, lane = threadIdx.x & 63;
  int row = blockIdx.x * 4 + wid;     // (b*12+h)*1024 + n
  int n  = row & 1023;
  int bh = row >> 10;
  int h  = bh % 12;
  int b  = bh / 12;
  float mq = means[0];
  float qv = b2f(q[((size_t)row << 6) + lane]);
  unsigned long long qmask = __ballot((qv - mq) > 0.f);
  const float* ap = attn + ((size_t)bh << 12) + lane;
  float acc = 0.f;
#pragma unroll 4
  for (int dd = 0; dd < 64; ++dd) {
    if ((qmask >> dd) & 1ull) acc += ap[dd * 64];
  }
  float vv = b2f(v[((size_t)row << 6) + lane]);
  float o = 0.5f * vv + acc * 0.3183098861837907f;
  float ss = o * o;
#pragma unroll
  for (int off = 32; off; off >>= 1) ss += __shfl_xor(ss, off);
  o *= rsqrtf(ss);
  const short* vrow = v + ((size_t)bh << 16);
#pragma unroll
  for (int j = 0; j < KRES_; ++j) {
    int nn = n + j - 4;
    if (nn >= 0 && nn < N_TOK)
      o += wd[h * 9 + j] * b2f(vrow[(nn << 6) + lane]);
  }
  mid[(size_t)((b << 10) | n) * 768 + h * 64 + lane] = f2b(o);
}

extern "C" void kernel_launch(void* const* d_in, const int* in_sizes, int n_in,
                              void* d_out, int out_size, void* d_ws, size_t ws_size,
                              hipStream_t stream) {
  (void)in_sizes; (void)n_in; (void)out_size; (void)ws_size;
  const float* x       = (const float*)d_in[0];
  const float* w_qkv   = (const float*)d_in[3];
  const float* w_dconv = (const float*)d_in[4];
  const float* w_proj  = (const float*)d_in[5];
  const float* b_proj  = (const float*)d_in[6];

  char* ws = (char*)d_ws;
  short* qbuf = (short*)ws;
  short* kbuf = qbuf + QKV_E;
  short* vbuf = kbuf + QKV_E;
  float* attn = (float*)(ws + (size_t)3 * QKV_E * 2);            // 75.5 MB in
  short* mid  = (short*)((char*)attn + (size_t)192 * 4096 * 4);  // +3.1 MB
  float* partials = (float*)((char*)mid + (size_t)16384 * 768 * 2); // +25.2 MB
  float* means = partials + 2 * NBLK2;

  // 1) QKV GEMM: x[16384,768] @ w_qkv[768,2304] -> q,k,v bf16 [B,h,N,d]
  dim3 g1(2304 / 64, 16384 / 64);
  gemm_mfma<0, false><<<g1, 256, 0, stream>>>(x, w_qkv, 2304, 768,
                                              qbuf, nullptr, nullptr);
  // 2) normalize q,k rows + partial sums for global means
  norm_mean_kernel<<<NBLK2, 256, 0, stream>>>(qbuf, kbuf, partials);
  mean_reduce_kernel<<<1, 256, 0, stream>>>(partials, means);
  // 3) attn = binarized(k)^T v per (b,h)
  attn_kernel<<<B_ * HEADS_, 256, 0, stream>>>(kbuf, vbuf, means, attn);
  // 4) out rows: 0.5v + q.attn/pi, normalize, + dconv -> mid bf16 [B,N,768]
  out_kernel<<<NBLK2, 256, 0, stream>>>(qbuf, vbuf, attn, means, w_dconv, mid);
  // 5) projection: mid[16384,768] @ w_proj[768,768] + b_proj -> d_out f32
  dim3 g2(768 / 64, 16384 / 64);
  gemm_mfma<1, true><<<g2, 256, 0, stream>>>(mid, w_proj, 768, 768,
                                             nullptr, (float*)d_out, b_proj);
}

// Round 2
// 849.739 us; speedup vs baseline: 1.5689x; 1.5689x over previous
//
#include <hip/hip_runtime.h>
#include <hip/hip_bf16.h>

#define B_      16
#define N_TOK   1024
#define DIM_    768
#define HEADS_  12
#define DHEAD   64
#define KRES_   9

#define QKV_E   (12582912)           // B*HEADS*N*DHEAD
#define ROWS_   (B_*HEADS_*N_TOK)    // 196608
#define NBLK2   (ROWS_/4)            // 49152
#define NCH     8                    // attn n-chunks per (b,h)

typedef __attribute__((ext_vector_type(8))) short bf16x8;
typedef __attribute__((ext_vector_type(4))) float f32x4;

__device__ inline short f2b(float f) {
  unsigned u = __builtin_bit_cast(unsigned, f);
  u += 0x7fff + ((u >> 16) & 1);   // round-to-nearest-even
  return (short)(u >> 16);
}
__device__ inline float b2f(short s) {
  unsigned u = ((unsigned)(unsigned short)s) << 16;
  return __builtin_bit_cast(float, u);
}

// ---------------------------------------------------------------------------
// Generic bf16-MFMA GEMM: C[M,N] = A[M,K] * B[K,N]
// 64x64 tile per 256-thread block (4 waves, each wave: 16 rows x 64 cols).
// MODE 0: scatter-write bf16 into q/k/v [B,h,N,d] buffers (QKV gemm, N=2304)
// MODE 1: write f32 + bias to out (projection gemm, N=768)
// ---------------------------------------------------------------------------
template<int MODE, bool ABF16>
__global__ __launch_bounds__(256) void gemm_mfma(
    const void* __restrict__ Araw, const float* __restrict__ Bmat,
    int N, int K,
    short* __restrict__ qkv_out, float* __restrict__ proj_out,
    const float* __restrict__ bias)
{
  __shared__ short As[64 * 40];
  __shared__ short Bs[64 * 40];

  const int tid  = threadIdx.x;
  const int lane = tid & 63;
  const int wid  = tid >> 6;
  const int rowBase = blockIdx.y << 6;
  const int colBase = blockIdx.x << 6;

  const int sr  = tid >> 2;          // staging row / col-of-B: 0..63
  const int skg = (tid & 3) << 3;    // staging k offset: 0,8,16,24

  const int fr  = lane & 15;         // fragment row (A) / col (B)
  const int fko = (lane >> 4) << 3;  // fragment k offset

  const float* Af = (const float*)Araw;
  const short* Ab = (const short*)Araw;

  f32x4 acc[4];
#pragma unroll
  for (int i = 0; i < 4; ++i) acc[i] = f32x4{0.f, 0.f, 0.f, 0.f};

  for (int k0 = 0; k0 < K; k0 += 32) {
    __syncthreads();
    // ---- stage A tile (convert f32->bf16 if needed) ----
    bf16x8 av;
    if (ABF16) {
      av = *(const bf16x8*)(Ab + (size_t)(rowBase + sr) * K + k0 + skg);
    } else {
      const float* ap = Af + (size_t)(rowBase + sr) * K + k0 + skg;
      float4 a0 = *(const float4*)ap;
      float4 a1 = *(const float4*)(ap + 4);
      av[0]=f2b(a0.x); av[1]=f2b(a0.y); av[2]=f2b(a0.z); av[3]=f2b(a0.w);
      av[4]=f2b(a1.x); av[5]=f2b(a1.y); av[6]=f2b(a1.z); av[7]=f2b(a1.w);
    }
    *(bf16x8*)(As + sr * 40 + skg) = av;
    // ---- stage B tile transposed: Bs[n][k] ----
    {
      const float* bp = Bmat + (size_t)(k0 + skg) * N + colBase + sr;
      bf16x8 bv;
#pragma unroll
      for (int j = 0; j < 8; ++j) bv[j] = f2b(bp[(size_t)j * N]);
      *(bf16x8*)(Bs + sr * 40 + skg) = bv;
    }
    __syncthreads();
    // ---- MFMA ----
    bf16x8 af = *(const bf16x8*)(As + (wid * 16 + fr) * 40 + fko);
#pragma unroll
    for (int nt = 0; nt < 4; ++nt) {
      bf16x8 bfr = *(const bf16x8*)(Bs + (nt * 16 + fr) * 40 + fko);
      acc[nt] = __builtin_amdgcn_mfma_f32_16x16x32_bf16(af, bfr, acc[nt], 0, 0, 0);
    }
  }

  // ---- epilogue: D layout col = lane&15, row = (lane>>4)*4 + e ----
#pragma unroll
  for (int nt = 0; nt < 4; ++nt) {
#pragma unroll
    for (int e = 0; e < 4; ++e) {
      int gr = rowBase + wid * 16 + ((lane >> 4) << 2) + e;
      int gc = colBase + nt * 16 + fr;
      float val = acc[nt][e];
      if (MODE == 0) {
        int part = gc / 768;
        int hd   = (gc % 768) / 64;
        int dd   = gc & 63;
        int b    = gr >> 10;
        int n    = gr & 1023;
        size_t idx = (size_t)part * QKV_E
                   + ((size_t)((b * 12 + hd) * 1024 + n) << 6) + dd;
        qkv_out[idx] = f2b(val);
      } else {
        proj_out[(size_t)gr * N + gc] = val + bias[gc];
      }
    }
  }
}

// ---------------------------------------------------------------------------
// Normalize q,k rows (64 elems) in place; emit per-block sums of normalized
// values for the global means. One wave per (b,h,n) row; 4 rows per block.
// ---------------------------------------------------------------------------
__global__ __launch_bounds__(256) void norm_mean_kernel(
    short* __restrict__ q, short* __restrict__ k, float* __restrict__ partials)
{
  int wid = threadIdx.x >> 6, lane = threadIdx.x & 63;
  int row = blockIdx.x * 4 + wid;
  size_t base = ((size_t)row << 6) + lane;
  float qv = b2f(q[base]), kv = b2f(k[base]);
  float qss = qv * qv, kss = kv * kv;
#pragma unroll
  for (int o = 32; o; o >>= 1) { qss += __shfl_xor(qss, o); kss += __shfl_xor(kss, o); }
  float qn = qv * rsqrtf(qss), kn = kv * rsqrtf(kss);
  q[base] = f2b(qn); k[base] = f2b(kn);
  float qs = qn, ks = kn;
#pragma unroll
  for (int o = 32; o; o >>= 1) { qs += __shfl_xor(qs, o); ks += __shfl_xor(ks, o); }
  __shared__ float sq[4], sk[4];
  if (lane == 0) { sq[wid] = qs; sk[wid] = ks; }
  __syncthreads();
  if (threadIdx.x == 0) {
    partials[blockIdx.x]         = sq[0] + sq[1] + sq[2] + sq[3];
    partials[NBLK2 + blockIdx.x] = sk[0] + sk[1] + sk[2] + sk[3];
  }
}

__global__ __launch_bounds__(256) void mean_reduce_kernel(
    const float* __restrict__ partials, float* __restrict__ means)
{
  float sq = 0.f, sk = 0.f;
  for (int i = threadIdx.x; i < NBLK2; i += 256) {
    sq += partials[i]; sk += partials[NBLK2 + i];
  }
#pragma unroll
  for (int o = 32; o; o >>= 1) { sq += __shfl_xor(sq, o); sk += __shfl_xor(sk, o); }
  __shared__ float s[8];
  int wid = threadIdx.x >> 6, lane = threadIdx.x & 63;
  if (lane == 0) { s[wid] = sq; s[4 + wid] = sk; }
  __syncthreads();
  if (threadIdx.x == 0) {
    means[0] = (s[0] + s[1] + s[2] + s[3]) / 12582912.f;
    means[1] = (s[4] + s[5] + s[6] + s[7]) / 12582912.f;
  }
}

// ---------------------------------------------------------------------------
// attn partials: part[bh*NCH+ch][d][e] = sum over 128-token chunk of
// 1[k_norm > mean_k] * v.  1536 blocks -> real occupancy (was 192 blocks,
// 574us at 8.9% occupancy). Deterministic (no atomics).
// ---------------------------------------------------------------------------
__global__ __launch_bounds__(256) void attn_part_kernel(
    const short* __restrict__ k, const short* __restrict__ v,
    const float* __restrict__ means, float* __restrict__ part)
{
  int bh = blockIdx.x / NCH;
  int ch = blockIdx.x % NCH;
  int dd = threadIdx.x >> 2;
  int e0 = (threadIdx.x & 3) << 4;
  float mk = means[1];
  float acc[16];
#pragma unroll
  for (int i = 0; i < 16; ++i) acc[i] = 0.f;
  const short* kb = k + ((size_t)bh << 16) + (ch << 13);  // ch*128 rows *64
  const short* vb = v + ((size_t)bh << 16) + (ch << 13);
  for (int n = 0; n < N_TOK / NCH; ++n) {
    bool on = (b2f(kb[(n << 6) + dd]) - mk) > 0.f;
    if (on) {
      const short* vp = vb + (n << 6) + e0;
      bf16x8 v0 = *(const bf16x8*)(vp);
      bf16x8 v1 = *(const bf16x8*)(vp + 8);
#pragma unroll
      for (int i = 0; i < 8; ++i) { acc[i] += b2f(v0[i]); acc[8 + i] += b2f(v1[i]); }
    }
  }
  float* pp = part + ((size_t)blockIdx.x << 12) + dd * 64 + e0;
#pragma unroll
  for (int i = 0; i < 16; ++i) pp[i] = acc[i];
}

__global__ __launch_bounds__(256) void attn_reduce_kernel(
    const float* __restrict__ part, float* __restrict__ attn)
{
  int idx = blockIdx.x * 256 + threadIdx.x;   // over 192*4096
  int bh  = idx >> 12;
  int off = idx & 4095;
  float s = 0.f;
#pragma unroll
  for (int c = 0; c < NCH; ++c)
    s += part[(((size_t)bh * NCH + c) << 12) + off];
  attn[idx] = s;
}

// ---------------------------------------------------------------------------
// out row: o = 0.5 v + (1/pi) * qbits . attn ; normalize ; + depthwise conv ;
// write bf16 into mid[B,N,768]. One wave per (b,h,n) row.
// ---------------------------------------------------------------------------
__global__ __launch_bounds__(256) void out_kernel(
    const short* __restrict__ q, const short* __restrict__ v,
    const float* __restrict__ attn, const float* __restrict__ means,
    const float* __restrict__ wd, short* __restrict__ mid)
{
  int wid = threadIdx.x >> 6, lane = threadIdx.x & 63;
  int row = blockIdx.x * 4 + wid;     // (b*12+h)*1024 + n
  int n  = row & 1023;
  int bh = row >> 10;
  int h  = bh % 12;
  int b  = bh / 12;
  float mq = means[0];
  float qv = b2f(q[((size_t)row << 6) + lane]);
  unsigned long long qmask = __ballot((qv - mq) > 0.f);
  const float* ap = attn + ((size_t)bh << 12) + lane;
  float acc = 0.f;
#pragma unroll 4
  for (int dd = 0; dd < 64; ++dd) {
    if ((qmask >> dd) & 1ull) acc += ap[dd * 64];
  }
  float vv = b2f(v[((size_t)row << 6) + lane]);
  float o = 0.5f * vv + acc * 0.3183098861837907f;
  float ss = o * o;
#pragma unroll
  for (int off = 32; off; off >>= 1) ss += __shfl_xor(ss, off);
  o *= rsqrtf(ss);
  const short* vrow = v + ((size_t)bh << 16);
#pragma unroll
  for (int j = 0; j < KRES_; ++j) {
    int nn = n + j - 4;
    if (nn >= 0 && nn < N_TOK)
      o += wd[h * 9 + j] * b2f(vrow[(nn << 6) + lane]);
  }
  mid[(size_t)((b << 10) | n) * 768 + h * 64 + lane] = f2b(o);
}

extern "C" void kernel_launch(void* const* d_in, const int* in_sizes, int n_in,
                              void* d_out, int out_size, void* d_ws, size_t ws_size,
                              hipStream_t stream) {
  (void)in_sizes; (void)n_in; (void)out_size; (void)ws_size;
  const float* x       = (const float*)d_in[0];
  const float* w_qkv   = (const float*)d_in[3];
  const float* w_dconv = (const float*)d_in[4];
  const float* w_proj  = (const float*)d_in[5];
  const float* b_proj  = (const float*)d_in[6];

  char* ws = (char*)d_ws;
  short* qbuf = (short*)ws;
  short* kbuf = qbuf + QKV_E;
  short* vbuf = kbuf + QKV_E;
  float* attn = (float*)(ws + (size_t)3 * QKV_E * 2);            // 75.5 MB in
  short* mid  = (short*)((char*)attn + (size_t)192 * 4096 * 4);  // +3.1 MB
  // attn partials alias the mid region (mid not written until after reduce)
  float* attn_part = (float*)mid;                                 // 25.2 MB
  float* partials = (float*)((char*)mid + (size_t)16384 * 768 * 2); // +25.2 MB
  float* means = partials + 2 * NBLK2;

  // 1) QKV GEMM: x[16384,768] @ w_qkv[768,2304] -> q,k,v bf16 [B,h,N,d]
  dim3 g1(2304 / 64, 16384 / 64);
  gemm_mfma<0, false><<<g1, 256, 0, stream>>>(x, w_qkv, 2304, 768,
                                              qbuf, nullptr, nullptr);
  // 2) normalize q,k rows + partial sums for global means
  norm_mean_kernel<<<NBLK2, 256, 0, stream>>>(qbuf, kbuf, partials);
  mean_reduce_kernel<<<1, 256, 0, stream>>>(partials, means);
  // 3) attn = binarized(k)^T v per (b,h), chunked over n then reduced
  attn_part_kernel<<<B_ * HEADS_ * NCH, 256, 0, stream>>>(kbuf, vbuf, means, attn_part);
  attn_reduce_kernel<<<B_ * HEADS_ * 4096 / 256, 256, 0, stream>>>(attn_part, attn);
  // 4) out rows: 0.5v + q.attn/pi, normalize, + dconv -> mid bf16 [B,N,768]
  out_kernel<<<NBLK2, 256, 0, stream>>>(qbuf, vbuf, attn, means, w_dconv, mid);
  // 5) projection: mid[16384,768] @ w_proj[768,768] + b_proj -> d_out f32
  dim3 g2(768 / 64, 16384 / 64);
  gemm_mfma<1, true><<<g2, 256, 0, stream>>>(mid, w_proj, 768, 768,
                                             nullptr, (float*)d_out, b_proj);
}

// Round 3
// 636.066 us; speedup vs baseline: 2.0960x; 1.3359x over previous
//
#include <hip/hip_runtime.h>
#include <hip/hip_bf16.h>

#define B_      16
#define N_TOK   1024
#define DIM_    768
#define HEADS_  12
#define DHEAD   64
#define KRES_   9

#define QKV_E   (12582912)           // B*HEADS*N*DHEAD
#define ROWS_   (B_*HEADS_*N_TOK)    // 196608
#define NBLK2   (ROWS_/4)            // 49152
#define NCH     8                    // attn n-chunks per (b,h)

typedef __attribute__((ext_vector_type(8))) short bf16x8;
typedef __attribute__((ext_vector_type(4))) short s16x4;
typedef __attribute__((ext_vector_type(4))) float f32x4;

__device__ inline short f2b(float f) {
  unsigned u = __builtin_bit_cast(unsigned, f);
  u += 0x7fff + ((u >> 16) & 1);   // round-to-nearest-even
  return (short)(u >> 16);
}
__device__ inline float b2f(short s) {
  unsigned u = ((unsigned)(unsigned short)s) << 16;
  return __builtin_bit_cast(float, u);
}

__device__ inline void gload16(const short* g, short* l) {
  __builtin_amdgcn_global_load_lds(
      (const __attribute__((address_space(1))) void*)g,
      (__attribute__((address_space(3))) void*)l, 16, 0, 0);
}

// ---------------------------------------------------------------------------
// x (f32) -> bf16, vectorized 8/thread
// ---------------------------------------------------------------------------
__global__ __launch_bounds__(256) void cvt_bf16_kernel(
    const float* __restrict__ in, short* __restrict__ out, int n8)
{
  int i = blockIdx.x * 256 + threadIdx.x;
  if (i >= n8) return;
  float4 a = ((const float4*)in)[2 * i];
  float4 b = ((const float4*)in)[2 * i + 1];
  bf16x8 v;
  v[0]=f2b(a.x); v[1]=f2b(a.y); v[2]=f2b(a.z); v[3]=f2b(a.w);
  v[4]=f2b(b.x); v[5]=f2b(b.y); v[6]=f2b(b.z); v[7]=f2b(b.w);
  ((bf16x8*)out)[i] = v;
}

// ---------------------------------------------------------------------------
// f32 [R][C] -> bf16 [C][R] (64x64 LDS tiles). R,C multiples of 64.
// ---------------------------------------------------------------------------
__global__ __launch_bounds__(256) void transpose_cvt_kernel(
    const float* __restrict__ in, short* __restrict__ out, int R, int C)
{
  __shared__ short t[64][65];
  int c0 = blockIdx.x * 64, r0 = blockIdx.y * 64;
#pragma unroll
  for (int p = 0; p < 4; ++p) {
    int r = (threadIdx.x >> 4) + p * 16;
    int c = (threadIdx.x & 15) * 4;
    float4 v = *(const float4*)(in + (size_t)(r0 + r) * C + c0 + c);
    t[c][r] = f2b(v.x); t[c + 1][r] = f2b(v.y);
    t[c + 2][r] = f2b(v.z); t[c + 3][r] = f2b(v.w);
  }
  __syncthreads();
#pragma unroll
  for (int p = 0; p < 4; ++p) {
    int oc = (threadIdx.x >> 4) + p * 16;
    int orr = (threadIdx.x & 15) * 4;
    s16x4 v = { t[oc][orr], t[oc][orr + 1], t[oc][orr + 2], t[oc][orr + 3] };
    *(s16x4*)(out + (size_t)(c0 + oc) * R + r0 + orr) = v;
  }
}

// ---------------------------------------------------------------------------
// m97-structure GEMM: C[M,N] = A[M,K] * BT[N,K]^T, both bf16 row-major.
// 128x128 tile, 256 thr / 4 waves, each wave 64x64 out (4x4 16x16 frags),
// BK=32, global_load_lds width-16 staging into linear LDS [128][32].
// MODE 0: scatter bf16 -> q/k/v [B,h,N,d];  MODE 1: f32 + bias -> out.
// ---------------------------------------------------------------------------
template<int MODE>
__global__ __launch_bounds__(256) void gemm128(
    const short* __restrict__ A, const short* __restrict__ BT,
    int N, int K,
    short* __restrict__ qkv_out, float* __restrict__ proj_out,
    const float* __restrict__ bias)
{
  __shared__ short As[128 * 32];
  __shared__ short Bs[128 * 32];

  const int tid  = threadIdx.x;
  const int lane = tid & 63;
  const int wid  = tid >> 6;
  const int wr   = wid >> 1, wc = wid & 1;
  const int rowBase = blockIdx.y << 7;
  const int colBase = blockIdx.x << 7;

  const int fr  = lane & 15;
  const int fko = (lane >> 4) << 3;

  const int srow = tid >> 2;          // staging row 0..63 (per half)
  const int skg  = (tid & 3) << 3;    // staging k offset (elems)

  const short* Ab = A  + (size_t)rowBase * K;
  const short* Bb = BT + (size_t)colBase * K;

  f32x4 acc[4][4];
#pragma unroll
  for (int i = 0; i < 4; ++i)
#pragma unroll
    for (int j = 0; j < 4; ++j) acc[i][j] = f32x4{0.f, 0.f, 0.f, 0.f};

  for (int k0 = 0; k0 < K; k0 += 32) {
    __syncthreads();
    gload16(Ab + (size_t)srow * K + k0 + skg,        As + srow * 32 + skg);
    gload16(Ab + (size_t)(64 + srow) * K + k0 + skg, As + (64 + srow) * 32 + skg);
    gload16(Bb + (size_t)srow * K + k0 + skg,        Bs + srow * 32 + skg);
    gload16(Bb + (size_t)(64 + srow) * K + k0 + skg, Bs + (64 + srow) * 32 + skg);
    __syncthreads();

    bf16x8 a[4], b[4];
#pragma unroll
    for (int i = 0; i < 4; ++i)
      a[i] = *(const bf16x8*)(As + (wr * 64 + i * 16 + fr) * 32 + fko);
#pragma unroll
    for (int j = 0; j < 4; ++j)
      b[j] = *(const bf16x8*)(Bs + (wc * 64 + j * 16 + fr) * 32 + fko);
#pragma unroll
    for (int i = 0; i < 4; ++i)
#pragma unroll
      for (int j = 0; j < 4; ++j)
        acc[i][j] = __builtin_amdgcn_mfma_f32_16x16x32_bf16(a[i], b[j], acc[i][j], 0, 0, 0);
  }

  // epilogue: D frag layout col = lane&15, row = (lane>>4)*4 + e
#pragma unroll
  for (int i = 0; i < 4; ++i)
#pragma unroll
    for (int j = 0; j < 4; ++j)
#pragma unroll
      for (int e = 0; e < 4; ++e) {
        int gr = rowBase + wr * 64 + i * 16 + ((lane >> 4) << 2) + e;
        int gc = colBase + wc * 64 + j * 16 + fr;
        float val = acc[i][j][e];
        if (MODE == 0) {
          int part = gc / 768;
          int hd   = (gc % 768) / 64;
          int dd   = gc & 63;
          int b    = gr >> 10;
          int n    = gr & 1023;
          size_t idx = (size_t)part * QKV_E
                     + ((size_t)((b * 12 + hd) * 1024 + n) << 6) + dd;
          qkv_out[idx] = f2b(val);
        } else {
          proj_out[(size_t)gr * N + gc] = val + bias[gc];
        }
      }
}

// ---------------------------------------------------------------------------
// Normalize q,k rows (64 elems) in place; per-block sums for global means.
// ---------------------------------------------------------------------------
__global__ __launch_bounds__(256) void norm_mean_kernel(
    short* __restrict__ q, short* __restrict__ k, float* __restrict__ partials)
{
  int wid = threadIdx.x >> 6, lane = threadIdx.x & 63;
  int row = blockIdx.x * 4 + wid;
  size_t base = ((size_t)row << 6) + lane;
  float qv = b2f(q[base]), kv = b2f(k[base]);
  float qss = qv * qv, kss = kv * kv;
#pragma unroll
  for (int o = 32; o; o >>= 1) { qss += __shfl_xor(qss, o); kss += __shfl_xor(kss, o); }
  float qn = qv * rsqrtf(qss), kn = kv * rsqrtf(kss);
  q[base] = f2b(qn); k[base] = f2b(kn);
  float qs = qn, ks = kn;
#pragma unroll
  for (int o = 32; o; o >>= 1) { qs += __shfl_xor(qs, o); ks += __shfl_xor(ks, o); }
  __shared__ float sq[4], sk[4];
  if (lane == 0) { sq[wid] = qs; sk[wid] = ks; }
  __syncthreads();
  if (threadIdx.x == 0) {
    partials[blockIdx.x]         = sq[0] + sq[1] + sq[2] + sq[3];
    partials[NBLK2 + blockIdx.x] = sk[0] + sk[1] + sk[2] + sk[3];
  }
}

__global__ __launch_bounds__(256) void mean_reduce_kernel(
    const float* __restrict__ partials, float* __restrict__ means)
{
  float sq = 0.f, sk = 0.f;
  for (int i = threadIdx.x; i < NBLK2; i += 256) {
    sq += partials[i]; sk += partials[NBLK2 + i];
  }
#pragma unroll
  for (int o = 32; o; o >>= 1) { sq += __shfl_xor(sq, o); sk += __shfl_xor(sk, o); }
  __shared__ float s[8];
  int wid = threadIdx.x >> 6, lane = threadIdx.x & 63;
  if (lane == 0) { s[wid] = sq; s[4 + wid] = sk; }
  __syncthreads();
  if (threadIdx.x == 0) {
    means[0] = (s[0] + s[1] + s[2] + s[3]) / 12582912.f;
    means[1] = (s[4] + s[5] + s[6] + s[7]) / 12582912.f;
  }
}

// ---------------------------------------------------------------------------
// attn partials over 128-token chunks; deterministic tree reduce after.
// ---------------------------------------------------------------------------
__global__ __launch_bounds__(256) void attn_part_kernel(
    const short* __restrict__ k, const short* __restrict__ v,
    const float* __restrict__ means, float* __restrict__ part)
{
  int bh = blockIdx.x / NCH;
  int ch = blockIdx.x % NCH;
  int dd = threadIdx.x >> 2;
  int e0 = (threadIdx.x & 3) << 4;
  float mk = means[1];
  float acc[16];
#pragma unroll
  for (int i = 0; i < 16; ++i) acc[i] = 0.f;
  const short* kb = k + ((size_t)bh << 16) + (ch << 13);
  const short* vb = v + ((size_t)bh << 16) + (ch << 13);
  for (int n = 0; n < N_TOK / NCH; ++n) {
    bool on = (b2f(kb[(n << 6) + dd]) - mk) > 0.f;
    if (on) {
      const short* vp = vb + (n << 6) + e0;
      bf16x8 v0 = *(const bf16x8*)(vp);
      bf16x8 v1 = *(const bf16x8*)(vp + 8);
#pragma unroll
      for (int i = 0; i < 8; ++i) { acc[i] += b2f(v0[i]); acc[8 + i] += b2f(v1[i]); }
    }
  }
  float* pp = part + ((size_t)blockIdx.x << 12) + dd * 64 + e0;
#pragma unroll
  for (int i = 0; i < 16; ++i) pp[i] = acc[i];
}

__global__ __launch_bounds__(256) void attn_reduce_kernel(
    const float* __restrict__ part, float* __restrict__ attn)
{
  int idx = blockIdx.x * 256 + threadIdx.x;   // over 192*4096
  int bh  = idx >> 12;
  int off = idx & 4095;
  float s = 0.f;
#pragma unroll
  for (int c = 0; c < NCH; ++c)
    s += part[(((size_t)bh * NCH + c) << 12) + off];
  attn[idx] = s;
}

// ---------------------------------------------------------------------------
// out row: 0.5 v + (1/pi) qbits.attn ; normalize ; + depthwise conv -> mid
// ---------------------------------------------------------------------------
__global__ __launch_bounds__(256) void out_kernel(
    const short* __restrict__ q, const short* __restrict__ v,
    const float* __restrict__ attn, const float* __restrict__ means,
    const float* __restrict__ wd, short* __restrict__ mid)
{
  int wid = threadIdx.x >> 6, lane = threadIdx.x & 63;
  int row = blockIdx.x * 4 + wid;     // (b*12+h)*1024 + n
  int n  = row & 1023;
  int bh = row >> 10;
  int h  = bh % 12;
  int b  = bh / 12;
  float mq = means[0];
  float qv = b2f(q[((size_t)row << 6) + lane]);
  unsigned long long qmask = __ballot((qv - mq) > 0.f);
  const float* ap = attn + ((size_t)bh << 12) + lane;
  float acc = 0.f;
#pragma unroll 4
  for (int dd = 0; dd < 64; ++dd) {
    if ((qmask >> dd) & 1ull) acc += ap[dd * 64];
  }
  float vv = b2f(v[((size_t)row << 6) + lane]);
  float o = 0.5f * vv + acc * 0.3183098861837907f;
  float ss = o * o;
#pragma unroll
  for (int off = 32; off; off >>= 1) ss += __shfl_xor(ss, off);
  o *= rsqrtf(ss);
  const short* vrow = v + ((size_t)bh << 16);
#pragma unroll
  for (int j = 0; j < KRES_; ++j) {
    int nn = n + j - 4;
    if (nn >= 0 && nn < N_TOK)
      o += wd[h * 9 + j] * b2f(vrow[(nn << 6) + lane]);
  }
  mid[(size_t)((b << 10) | n) * 768 + h * 64 + lane] = f2b(o);
}

extern "C" void kernel_launch(void* const* d_in, const int* in_sizes, int n_in,
                              void* d_out, int out_size, void* d_ws, size_t ws_size,
                              hipStream_t stream) {
  (void)in_sizes; (void)n_in; (void)out_size; (void)ws_size;
  const float* x       = (const float*)d_in[0];
  const float* w_qkv   = (const float*)d_in[3];
  const float* w_dconv = (const float*)d_in[4];
  const float* w_proj  = (const float*)d_in[5];
  const float* b_proj  = (const float*)d_in[6];

  // ---- workspace layout (with phase-safe aliasing), ~130.5 MB ----
  char* ws = (char*)d_ws;
  short* qbuf = (short*)ws;                         // 3*QKV_E shorts
  short* kbuf = qbuf + QKV_E;
  short* vbuf = kbuf + QKV_E;
  char*  r2   = ws + (size_t)3 * QKV_E * 2;         // 3.54 MB region:
  short* wqkvT    = (short*)r2;                     //   phases 0-1
  float* attn     = (float*)r2;                     //   phases 5-6 (3.15 MB)
  float* partials = (float*)(r2 + 3145728);         //   phases 2-3 (0.39 MB)
  short* mid  = (short*)(r2 + 3538944);             // 25.2 MB
  char*  r4   = (char*)mid + (size_t)16384 * 768 * 2;
  short* xb        = (short*)r4;                    // 25.2 MB, phases 0-1
  float* attn_part = (float*)r4;                    //   reused phases 4-5
  short* wprojT = (short*)(r4 + (size_t)QKV_E * 2); // 1.18 MB, phases 0,7
  float* means  = (float*)((char*)wprojT + (size_t)768 * 768 * 2);

  // 0) convert x -> bf16; transpose+convert weights
  cvt_bf16_kernel<<<QKV_E / 8 / 256, 256, 0, stream>>>(x, xb, QKV_E / 8);
  dim3 gt1(2304 / 64, 768 / 64);
  transpose_cvt_kernel<<<gt1, 256, 0, stream>>>(w_qkv, wqkvT, 768, 2304);
  dim3 gt2(768 / 64, 768 / 64);
  transpose_cvt_kernel<<<gt2, 256, 0, stream>>>(w_proj, wprojT, 768, 768);

  // 1) QKV GEMM: xb[16384,768] @ wqkvT[2304,768]^T -> q,k,v bf16 [B,h,N,d]
  dim3 g1(2304 / 128, 16384 / 128);
  gemm128<0><<<g1, 256, 0, stream>>>(xb, wqkvT, 2304, 768, qbuf, nullptr, nullptr);

  // 2-3) normalize q,k + global means
  norm_mean_kernel<<<NBLK2, 256, 0, stream>>>(qbuf, kbuf, partials);
  mean_reduce_kernel<<<1, 256, 0, stream>>>(partials, means);

  // 4-5) attn = binarized(k)^T v, chunked + reduced
  attn_part_kernel<<<B_ * HEADS_ * NCH, 256, 0, stream>>>(kbuf, vbuf, means, attn_part);
  attn_reduce_kernel<<<B_ * HEADS_ * 4096 / 256, 256, 0, stream>>>(attn_part, attn);

  // 6) out rows -> mid bf16 [B,N,768]
  out_kernel<<<NBLK2, 256, 0, stream>>>(qbuf, vbuf, attn, means, w_dconv, mid);

  // 7) projection: mid @ wprojT^T + b_proj -> d_out f32
  dim3 g2(768 / 128, 16384 / 128);
  gemm128<1><<<g2, 256, 0, stream>>>(mid, wprojT, 768, 768,
                                     nullptr, (float*)d_out, b_proj);
}

// Round 4
// 406.570 us; speedup vs baseline: 3.2791x; 1.5645x over previous
//
#include <hip/hip_runtime.h>
#include <hip/hip_bf16.h>

#define B_      16
#define N_TOK   1024
#define DIM_    768
#define HEADS_  12
#define DHEAD   64
#define KRES_   9

#define QKV_E   (12582912)           // B*HEADS*N*DHEAD
#define ROWS_   (B_*HEADS_*N_TOK)    // 196608
#define NBLK2   (ROWS_/4)            // 49152
#define NCH     8                    // attn n-chunks per (b,h)

typedef __attribute__((ext_vector_type(8))) short bf16x8;
typedef __attribute__((ext_vector_type(4))) short s16x4;
typedef __attribute__((ext_vector_type(4))) float f32x4;

__device__ inline short f2b(float f) {
  unsigned u = __builtin_bit_cast(unsigned, f);
  u += 0x7fff + ((u >> 16) & 1);   // round-to-nearest-even
  return (short)(u >> 16);
}
__device__ inline float b2f(short s) {
  unsigned u = ((unsigned)(unsigned short)s) << 16;
  return __builtin_bit_cast(float, u);
}

__device__ inline void gload16(const short* g, short* l) {
  __builtin_amdgcn_global_load_lds(
      (const __attribute__((address_space(1))) void*)g,
      (__attribute__((address_space(3))) void*)l, 16, 0, 0);
}

// ---------------------------------------------------------------------------
// x (f32) -> bf16, vectorized 8/thread
// ---------------------------------------------------------------------------
__global__ __launch_bounds__(256) void cvt_bf16_kernel(
    const float* __restrict__ in, short* __restrict__ out, int n8)
{
  int i = blockIdx.x * 256 + threadIdx.x;
  if (i >= n8) return;
  float4 a = ((const float4*)in)[2 * i];
  float4 b = ((const float4*)in)[2 * i + 1];
  bf16x8 v;
  v[0]=f2b(a.x); v[1]=f2b(a.y); v[2]=f2b(a.z); v[3]=f2b(a.w);
  v[4]=f2b(b.x); v[5]=f2b(b.y); v[6]=f2b(b.z); v[7]=f2b(b.w);
  ((bf16x8*)out)[i] = v;
}

// ---------------------------------------------------------------------------
// f32 [R][C] -> bf16 [C][R] (64x64 LDS tiles). R,C multiples of 64.
// ---------------------------------------------------------------------------
__global__ __launch_bounds__(256) void transpose_cvt_kernel(
    const float* __restrict__ in, short* __restrict__ out, int R, int C)
{
  __shared__ short t[64][65];
  int c0 = blockIdx.x * 64, r0 = blockIdx.y * 64;
#pragma unroll
  for (int p = 0; p < 4; ++p) {
    int r = (threadIdx.x >> 4) + p * 16;
    int c = (threadIdx.x & 15) * 4;
    float4 v = *(const float4*)(in + (size_t)(r0 + r) * C + c0 + c);
    t[c][r] = f2b(v.x); t[c + 1][r] = f2b(v.y);
    t[c + 2][r] = f2b(v.z); t[c + 3][r] = f2b(v.w);
  }
  __syncthreads();
#pragma unroll
  for (int p = 0; p < 4; ++p) {
    int oc = (threadIdx.x >> 4) + p * 16;
    int orr = (threadIdx.x & 15) * 4;
    s16x4 v = { t[oc][orr], t[oc][orr + 1], t[oc][orr + 2], t[oc][orr + 3] };
    *(s16x4*)(out + (size_t)(c0 + oc) * R + r0 + orr) = v;
  }
}

// ---------------------------------------------------------------------------
// m97-structure GEMM: C[M,N] = A[M,K] * BT[N,K]^T, both bf16 row-major.
// 128x128 tile, 256 thr / 4 waves, each wave 64x64 out (4x4 16x16 frags),
// BK=32, global_load_lds width-16 staging into linear LDS [128][32].
// MODE 0: scatter bf16 -> q/k/v [B,h,N,d];  MODE 1: f32 + bias -> out.
// ---------------------------------------------------------------------------
template<int MODE>
__global__ __launch_bounds__(256) void gemm128(
    const short* __restrict__ A, const short* __restrict__ BT,
    int N, int K,
    short* __restrict__ qkv_out, float* __restrict__ proj_out,
    const float* __restrict__ bias)
{
  __shared__ short As[128 * 32];
  __shared__ short Bs[128 * 32];

  const int tid  = threadIdx.x;
  const int lane = tid & 63;
  const int wid  = tid >> 6;
  const int wr   = wid >> 1, wc = wid & 1;
  const int rowBase = blockIdx.y << 7;
  const int colBase = blockIdx.x << 7;

  const int fr  = lane & 15;
  const int fko = (lane >> 4) << 3;

  const int srow = tid >> 2;          // staging row 0..63 (per half)
  const int skg  = (tid & 3) << 3;    // staging k offset (elems)

  const short* Ab = A  + (size_t)rowBase * K;
  const short* Bb = BT + (size_t)colBase * K;

  f32x4 acc[4][4];
#pragma unroll
  for (int i = 0; i < 4; ++i)
#pragma unroll
    for (int j = 0; j < 4; ++j) acc[i][j] = f32x4{0.f, 0.f, 0.f, 0.f};

  for (int k0 = 0; k0 < K; k0 += 32) {
    __syncthreads();
    gload16(Ab + (size_t)srow * K + k0 + skg,        As + srow * 32 + skg);
    gload16(Ab + (size_t)(64 + srow) * K + k0 + skg, As + (64 + srow) * 32 + skg);
    gload16(Bb + (size_t)srow * K + k0 + skg,        Bs + srow * 32 + skg);
    gload16(Bb + (size_t)(64 + srow) * K + k0 + skg, Bs + (64 + srow) * 32 + skg);
    __syncthreads();

    bf16x8 a[4], b[4];
#pragma unroll
    for (int i = 0; i < 4; ++i)
      a[i] = *(const bf16x8*)(As + (wr * 64 + i * 16 + fr) * 32 + fko);
#pragma unroll
    for (int j = 0; j < 4; ++j)
      b[j] = *(const bf16x8*)(Bs + (wc * 64 + j * 16 + fr) * 32 + fko);
#pragma unroll
    for (int i = 0; i < 4; ++i)
#pragma unroll
      for (int j = 0; j < 4; ++j)
        acc[i][j] = __builtin_amdgcn_mfma_f32_16x16x32_bf16(a[i], b[j], acc[i][j], 0, 0, 0);
  }

  // epilogue: D frag layout col = lane&15, row = (lane>>4)*4 + e
#pragma unroll
  for (int i = 0; i < 4; ++i)
#pragma unroll
    for (int j = 0; j < 4; ++j)
#pragma unroll
      for (int e = 0; e < 4; ++e) {
        int gr = rowBase + wr * 64 + i * 16 + ((lane >> 4) << 2) + e;
        int gc = colBase + wc * 64 + j * 16 + fr;
        float val = acc[i][j][e];
        if (MODE == 0) {
          int part = gc / 768;
          int hd   = (gc % 768) / 64;
          int dd   = gc & 63;
          int b    = gr >> 10;
          int n    = gr & 1023;
          size_t idx = (size_t)part * QKV_E
                     + ((size_t)((b * 12 + hd) * 1024 + n) << 6) + dd;
          qkv_out[idx] = f2b(val);
        } else {
          proj_out[(size_t)gr * N + gc] = val + bias[gc];
        }
      }
}

// ---------------------------------------------------------------------------
// Normalize q,k rows (64 elems) in place; per-block sums for global means.
// ---------------------------------------------------------------------------
__global__ __launch_bounds__(256) void norm_mean_kernel(
    short* __restrict__ q, short* __restrict__ k, float* __restrict__ partials)
{
  int wid = threadIdx.x >> 6, lane = threadIdx.x & 63;
  int row = blockIdx.x * 4 + wid;
  size_t base = ((size_t)row << 6) + lane;
  float qv = b2f(q[base]), kv = b2f(k[base]);
  float qss = qv * qv, kss = kv * kv;
#pragma unroll
  for (int o = 32; o; o >>= 1) { qss += __shfl_xor(qss, o); kss += __shfl_xor(kss, o); }
  float qn = qv * rsqrtf(qss), kn = kv * rsqrtf(kss);
  q[base] = f2b(qn); k[base] = f2b(kn);
  float qs = qn, ks = kn;
#pragma unroll
  for (int o = 32; o; o >>= 1) { qs += __shfl_xor(qs, o); ks += __shfl_xor(ks, o); }
  __shared__ float sq[4], sk[4];
  if (lane == 0) { sq[wid] = qs; sk[wid] = ks; }
  __syncthreads();
  if (threadIdx.x == 0) {
    partials[blockIdx.x]         = sq[0] + sq[1] + sq[2] + sq[3];
    partials[NBLK2 + blockIdx.x] = sk[0] + sk[1] + sk[2] + sk[3];
  }
}

__global__ __launch_bounds__(256) void mean_reduce_kernel(
    const float* __restrict__ partials, float* __restrict__ means)
{
  float sq = 0.f, sk = 0.f;
  for (int i = threadIdx.x; i < NBLK2; i += 256) {
    sq += partials[i]; sk += partials[NBLK2 + i];
  }
#pragma unroll
  for (int o = 32; o; o >>= 1) { sq += __shfl_xor(sq, o); sk += __shfl_xor(sk, o); }
  __shared__ float s[8];
  int wid = threadIdx.x >> 6, lane = threadIdx.x & 63;
  if (lane == 0) { s[wid] = sq; s[4 + wid] = sk; }
  __syncthreads();
  if (threadIdx.x == 0) {
    means[0] = (s[0] + s[1] + s[2] + s[3]) / 12582912.f;
    means[1] = (s[4] + s[5] + s[6] + s[7]) / 12582912.f;
  }
}

// ---------------------------------------------------------------------------
// attn partials over 128-token chunks; deterministic tree reduce after.
// ---------------------------------------------------------------------------
__global__ __launch_bounds__(256) void attn_part_kernel(
    const short* __restrict__ k, const short* __restrict__ v,
    const float* __restrict__ means, float* __restrict__ part)
{
  int bh = blockIdx.x / NCH;
  int ch = blockIdx.x % NCH;
  int dd = threadIdx.x >> 2;
  int e0 = (threadIdx.x & 3) << 4;
  float mk = means[1];
  float acc[16];
#pragma unroll
  for (int i = 0; i < 16; ++i) acc[i] = 0.f;
  const short* kb = k + ((size_t)bh << 16) + (ch << 13);
  const short* vb = v + ((size_t)bh << 16) + (ch << 13);
  for (int n = 0; n < N_TOK / NCH; ++n) {
    bool on = (b2f(kb[(n << 6) + dd]) - mk) > 0.f;
    if (on) {
      const short* vp = vb + (n << 6) + e0;
      bf16x8 v0 = *(const bf16x8*)(vp);
      bf16x8 v1 = *(const bf16x8*)(vp + 8);
#pragma unroll
      for (int i = 0; i < 8; ++i) { acc[i] += b2f(v0[i]); acc[8 + i] += b2f(v1[i]); }
    }
  }
  float* pp = part + ((size_t)blockIdx.x << 12) + dd * 64 + e0;
#pragma unroll
  for (int i = 0; i < 16; ++i) pp[i] = acc[i];
}

__global__ __launch_bounds__(256) void attn_reduce_kernel(
    const float* __restrict__ part, float* __restrict__ attn)
{
  int idx = blockIdx.x * 256 + threadIdx.x;   // over 192*4096
  int bh  = idx >> 12;
  int off = idx & 4095;
  float s = 0.f;
#pragma unroll
  for (int c = 0; c < NCH; ++c)
    s += part[(((size_t)bh * NCH + c) << 12) + off];
  attn[idx] = s;
}

// ---------------------------------------------------------------------------
// out rows: o = 0.5 v + (1/pi) qbits.attn ; normalize ; + depthwise conv.
// Block = 128 rows of one (b,h); 4 waves x 32 rows. Per wave the attn column
// attn[:,lane] is row-invariant -> hoisted into 64 VGPRs (kills the serial
// branchy-load chain that made this 307us). v window staged in LDS for conv.
// ---------------------------------------------------------------------------
__global__ __launch_bounds__(256) void out_kernel(
    const short* __restrict__ q, const short* __restrict__ v,
    const float* __restrict__ attn, const float* __restrict__ means,
    const float* __restrict__ wd, short* __restrict__ mid)
{
  __shared__ short v_s[136 * 64];     // rows n0-4 .. n0+131
  int tid = threadIdx.x, lane = tid & 63, wid = tid >> 6;
  int bh = blockIdx.x >> 3;
  int n0 = (blockIdx.x & 7) << 7;
  int h  = bh % 12;
  int b  = bh / 12;

  // stage v window
  const short* vb = v + ((size_t)bh << 16);
  for (int i = tid; i < 2176; i += 256) {   // 136*64/4 s16x4 vecs
    int r = i >> 4, c = (i & 15) << 2;
    int nn = n0 - 4 + r;
    s16x4 val = {0, 0, 0, 0};
    if (nn >= 0 && nn < N_TOK) val = *(const s16x4*)(vb + (nn << 6) + c);
    *(s16x4*)(v_s + (i << 2)) = val;
  }

  // hoist attn column attn[:,lane] into registers (row-invariant)
  const float* ag = attn + ((size_t)bh << 12) + lane;
  float col[64];
#pragma unroll
  for (int dd = 0; dd < 64; ++dd) col[dd] = ag[dd << 6];

  float mq = means[0];
  float wc[9];
#pragma unroll
  for (int j = 0; j < 9; ++j) wc[j] = wd[h * 9 + j];
  __syncthreads();

  const short* qb = q + ((size_t)bh << 16);
  for (int t = 0; t < 32; ++t) {
    int ln = (wid << 5) + t;          // local row 0..127
    int n  = n0 + ln;
    float qv = b2f(qb[(n << 6) + lane]);
    unsigned long long qmask = __ballot((qv - mq) > 0.f);
    float acc = 0.f;
#pragma unroll
    for (int dd = 0; dd < 64; ++dd) {
      float bitf = (float)((unsigned)((qmask >> dd) & 1ull));
      acc = fmaf(bitf, col[dd], acc);
    }
    float vv = b2f(v_s[((ln + 4) << 6) + lane]);
    float o = 0.5f * vv + acc * 0.3183098861837907f;
    float ss = o * o;
#pragma unroll
    for (int off = 32; off; off >>= 1) ss += __shfl_xor(ss, off);
    o *= rsqrtf(ss);
#pragma unroll
    for (int j = 0; j < 9; ++j)
      o += wc[j] * b2f(v_s[((ln + j) << 6) + lane]);
    mid[(size_t)((b << 10) | n) * 768 + (h << 6) + lane] = f2b(o);
  }
}

extern "C" void kernel_launch(void* const* d_in, const int* in_sizes, int n_in,
                              void* d_out, int out_size, void* d_ws, size_t ws_size,
                              hipStream_t stream) {
  (void)in_sizes; (void)n_in; (void)out_size; (void)ws_size;
  const float* x       = (const float*)d_in[0];
  const float* w_qkv   = (const float*)d_in[3];
  const float* w_dconv = (const float*)d_in[4];
  const float* w_proj  = (const float*)d_in[5];
  const float* b_proj  = (const float*)d_in[6];

  // ---- workspace layout (with phase-safe aliasing), ~130.5 MB ----
  char* ws = (char*)d_ws;
  short* qbuf = (short*)ws;                         // 3*QKV_E shorts
  short* kbuf = qbuf + QKV_E;
  short* vbuf = kbuf + QKV_E;
  char*  r2   = ws + (size_t)3 * QKV_E * 2;         // 3.54 MB region:
  short* wqkvT    = (short*)r2;                     //   phases 0-1
  float* attn     = (float*)r2;                     //   phases 5-6 (3.15 MB)
  float* partials = (float*)(r2 + 3145728);         //   phases 2-3 (0.39 MB)
  short* mid  = (short*)(r2 + 3538944);             // 25.2 MB
  char*  r4   = (char*)mid + (size_t)16384 * 768 * 2;
  short* xb        = (short*)r4;                    // 25.2 MB, phases 0-1
  float* attn_part = (float*)r4;                    //   reused phases 4-5
  short* wprojT = (short*)(r4 + (size_t)QKV_E * 2); // 1.18 MB, phases 0,7
  float* means  = (float*)((char*)wprojT + (size_t)768 * 768 * 2);

  // 0) convert x -> bf16; transpose+convert weights
  cvt_bf16_kernel<<<QKV_E / 8 / 256, 256, 0, stream>>>(x, xb, QKV_E / 8);
  dim3 gt1(2304 / 64, 768 / 64);
  transpose_cvt_kernel<<<gt1, 256, 0, stream>>>(w_qkv, wqkvT, 768, 2304);
  dim3 gt2(768 / 64, 768 / 64);
  transpose_cvt_kernel<<<gt2, 256, 0, stream>>>(w_proj, wprojT, 768, 768);

  // 1) QKV GEMM: xb[16384,768] @ wqkvT[2304,768]^T -> q,k,v bf16 [B,h,N,d]
  dim3 g1(2304 / 128, 16384 / 128);
  gemm128<0><<<g1, 256, 0, stream>>>(xb, wqkvT, 2304, 768, qbuf, nullptr, nullptr);

  // 2-3) normalize q,k + global means
  norm_mean_kernel<<<NBLK2, 256, 0, stream>>>(qbuf, kbuf, partials);
  mean_reduce_kernel<<<1, 256, 0, stream>>>(partials, means);

  // 4-5) attn = binarized(k)^T v, chunked + reduced
  attn_part_kernel<<<B_ * HEADS_ * NCH, 256, 0, stream>>>(kbuf, vbuf, means, attn_part);
  attn_reduce_kernel<<<B_ * HEADS_ * 4096 / 256, 256, 0, stream>>>(attn_part, attn);

  // 6) out rows -> mid bf16 [B,N,768]
  out_kernel<<<ROWS_ / 128, 256, 0, stream>>>(qbuf, vbuf, attn, means, w_dconv, mid);

  // 7) projection: mid @ wprojT^T + b_proj -> d_out f32
  dim3 g2(768 / 128, 16384 / 128);
  gemm128<1><<<g2, 256, 0, stream>>>(mid, wprojT, 768, 768,
                                     nullptr, (float*)d_out, b_proj);
}

// Round 5
// 380.428 us; speedup vs baseline: 3.5044x; 1.0687x over previous
//
#include <hip/hip_runtime.h>
#include <hip/hip_bf16.h>

#define B_      16
#define N_TOK   1024
#define DIM_    768
#define HEADS_  12
#define DHEAD   64
#define KRES_   9

#define QKV_E   (12582912)           // B*HEADS*N*DHEAD
#define ROWS_   (B_*HEADS_*N_TOK)    // 196608
#define NCH     8                    // attn n-chunks per (b,h)
#define NBLKNM  6144                 // norm_mean blocks (32 rows each)

typedef __attribute__((ext_vector_type(8))) short bf16x8;
typedef __attribute__((ext_vector_type(4))) short s16x4;
typedef __attribute__((ext_vector_type(4))) float f32x4;

__device__ inline short f2b(float f) {
  unsigned u = __builtin_bit_cast(unsigned, f);
  u += 0x7fff + ((u >> 16) & 1);   // round-to-nearest-even
  return (short)(u >> 16);
}
__device__ inline float b2f(short s) {
  unsigned u = ((unsigned)(unsigned short)s) << 16;
  return __builtin_bit_cast(float, u);
}

__device__ inline void gload16(const short* g, short* l) {
  __builtin_amdgcn_global_load_lds(
      (const __attribute__((address_space(1))) void*)g,
      (__attribute__((address_space(3))) void*)l, 16, 0, 0);
}

// ---------------------------------------------------------------------------
// x (f32) -> bf16, vectorized 8/thread
// ---------------------------------------------------------------------------
__global__ __launch_bounds__(256) void cvt_bf16_kernel(
    const float* __restrict__ in, short* __restrict__ out, int n8)
{
  int i = blockIdx.x * 256 + threadIdx.x;
  if (i >= n8) return;
  float4 a = ((const float4*)in)[2 * i];
  float4 b = ((const float4*)in)[2 * i + 1];
  bf16x8 v;
  v[0]=f2b(a.x); v[1]=f2b(a.y); v[2]=f2b(a.z); v[3]=f2b(a.w);
  v[4]=f2b(b.x); v[5]=f2b(b.y); v[6]=f2b(b.z); v[7]=f2b(b.w);
  ((bf16x8*)out)[i] = v;
}

// ---------------------------------------------------------------------------
// f32 [R][C] -> bf16 [C][R] (64x64 LDS tiles). R,C multiples of 64.
// ---------------------------------------------------------------------------
__global__ __launch_bounds__(256) void transpose_cvt_kernel(
    const float* __restrict__ in, short* __restrict__ out, int R, int C)
{
  __shared__ short t[64][65];
  int c0 = blockIdx.x * 64, r0 = blockIdx.y * 64;
#pragma unroll
  for (int p = 0; p < 4; ++p) {
    int r = (threadIdx.x >> 4) + p * 16;
    int c = (threadIdx.x & 15) * 4;
    float4 v = *(const float4*)(in + (size_t)(r0 + r) * C + c0 + c);
    t[c][r] = f2b(v.x); t[c + 1][r] = f2b(v.y);
    t[c + 2][r] = f2b(v.z); t[c + 3][r] = f2b(v.w);
  }
  __syncthreads();
#pragma unroll
  for (int p = 0; p < 4; ++p) {
    int oc = (threadIdx.x >> 4) + p * 16;
    int orr = (threadIdx.x & 15) * 4;
    s16x4 v = { t[oc][orr], t[oc][orr + 1], t[oc][orr + 2], t[oc][orr + 3] };
    *(s16x4*)(out + (size_t)(c0 + oc) * R + r0 + orr) = v;
  }
}

// ---------------------------------------------------------------------------
// m97-structure GEMM + dbuf prefetch: C[M,N] = A[M,K] * BT[N,K]^T (bf16).
// 128x128 tile, 256 thr / 4 waves, BK=32, global_load_lds w16 into linear
// LDS, DOUBLE-buffered: stage(next) issued BEFORE MFMAs, drained AFTER
// (raw s_barrier + explicit vmcnt so hipcc can't hoist the drain).
// 1-D grid + XCD-chunked bijective swizzle (col-fastest within chunk).
// MODE 0: scatter bf16 -> q/k/v [B,h,N,d];  MODE 1: f32 + bias -> out.
// ---------------------------------------------------------------------------
template<int MODE>
__global__ __launch_bounds__(256) void gemm128(
    const short* __restrict__ A, const short* __restrict__ BT,
    int N, int K, int nxblk,
    short* __restrict__ qkv_out, float* __restrict__ proj_out,
    const float* __restrict__ bias)
{
  __shared__ short As[2][128 * 32];
  __shared__ short Bs[2][128 * 32];

  const int tid  = threadIdx.x;
  const int lane = tid & 63;
  const int wid  = tid >> 6;
  const int wr   = wid >> 1, wc = wid & 1;

  // XCD swizzle: nwg%8==0 -> each XCD owns a contiguous col-fastest chunk
  const int nwg = (int)gridDim.x;
  const int cpx = nwg >> 3;
  const int swz = (blockIdx.x & 7) * cpx + (blockIdx.x >> 3);
  const int bx  = swz % nxblk, by = swz / nxblk;
  const int rowBase = by << 7;
  const int colBase = bx << 7;

  const int fr  = lane & 15;
  const int fko = (lane >> 4) << 3;

  const int srow = tid >> 2;
  const int skg  = (tid & 3) << 3;

  const short* Ap  = A  + (size_t)(rowBase + srow) * K + skg;
  const short* Bp  = BT + (size_t)(colBase + srow) * K + skg;
  const short* Ap2 = Ap + (size_t)64 * K;
  const short* Bp2 = Bp + (size_t)64 * K;
  short* dA  = &As[0][tid * 8];          // byte off = 16*tid (linear rule)
  short* dA2 = &As[0][2048 + tid * 8];
  short* dB  = &Bs[0][tid * 8];
  short* dB2 = &Bs[0][2048 + tid * 8];

  f32x4 acc[4][4];
#pragma unroll
  for (int i = 0; i < 4; ++i)
#pragma unroll
    for (int j = 0; j < 4; ++j) acc[i][j] = f32x4{0.f, 0.f, 0.f, 0.f};

#define STAGE(buf, k0)                                \
  do {                                                \
    gload16(Ap  + (k0), dA  + (buf) * 4096);          \
    gload16(Ap2 + (k0), dA2 + (buf) * 4096);          \
    gload16(Bp  + (k0), dB  + (buf) * 4096);          \
    gload16(Bp2 + (k0), dB2 + (buf) * 4096);          \
  } while (0)

  STAGE(0, 0);
  asm volatile("s_waitcnt vmcnt(0)" ::: "memory");
  __builtin_amdgcn_s_barrier();
  __builtin_amdgcn_sched_barrier(0);

  int cur = 0;
  for (int k0 = 0; k0 < K; k0 += 32) {
    const bool more = (k0 + 32 < K);
    if (more) STAGE(cur ^ 1, k0 + 32);   // loads in flight during MFMAs

    bf16x8 a[4], b[4];
#pragma unroll
    for (int i = 0; i < 4; ++i)
      a[i] = *(const bf16x8*)(&As[cur][(wr * 64 + i * 16 + fr) * 32 + fko]);
#pragma unroll
    for (int j = 0; j < 4; ++j)
      b[j] = *(const bf16x8*)(&Bs[cur][(wc * 64 + j * 16 + fr) * 32 + fko]);
#pragma unroll
    for (int i = 0; i < 4; ++i)
#pragma unroll
      for (int j = 0; j < 4; ++j)
        acc[i][j] = __builtin_amdgcn_mfma_f32_16x16x32_bf16(a[i], b[j], acc[i][j], 0, 0, 0);

    if (more) {
      asm volatile("s_waitcnt vmcnt(0)" ::: "memory");
      __builtin_amdgcn_s_barrier();
      __builtin_amdgcn_sched_barrier(0);
    }
    cur ^= 1;
  }
#undef STAGE

  // ---- epilogue: D frag layout col = lane&15, row = (lane>>4)*4 + e ----
  if (MODE == 0) {
    const int b  = rowBase >> 10;                      // tile stays in one b
    const int n0 = (rowBase & 1023) + wr * 64 + ((lane >> 4) << 2);
#pragma unroll
    for (int j = 0; j < 4; ++j) {
      int gc = colBase + wc * 64 + j * 16 + fr;
      int part = (gc >= 1536) ? 2 : (gc >= 768 ? 1 : 0);
      int rem  = gc - part * 768;
      int hd = rem >> 6, dd = rem & 63;
      size_t cbase = (size_t)part * QKV_E
                   + ((size_t)(b * 12 + hd) << 16) + dd;
#pragma unroll
      for (int i = 0; i < 4; ++i)
#pragma unroll
        for (int e = 0; e < 4; ++e)
          qkv_out[cbase + ((size_t)(n0 + i * 16 + e) << 6)] = f2b(acc[i][j][e]);
    }
  } else {
    const int gr0 = rowBase + wr * 64 + ((lane >> 4) << 2);
#pragma unroll
    for (int j = 0; j < 4; ++j) {
      int gc = colBase + wc * 64 + j * 16 + fr;
      float bj = bias[gc];
#pragma unroll
      for (int i = 0; i < 4; ++i)
#pragma unroll
        for (int e = 0; e < 4; ++e)
          proj_out[(size_t)(gr0 + i * 16 + e) * N + gc] = acc[i][j][e] + bj;
    }
  }
}

// ---------------------------------------------------------------------------
// Normalize q,k rows in place, vectorized: thread owns 8 elems; row = 8
// lanes; block = 32 rows. Per-block sums for the global means.
// ---------------------------------------------------------------------------
__global__ __launch_bounds__(256) void norm_mean_kernel(
    short* __restrict__ q, short* __restrict__ k, float* __restrict__ partials)
{
  int tid = threadIdx.x;
  size_t base = (size_t)blockIdx.x * 2048 + (size_t)tid * 8;
  bf16x8 qv8 = *(const bf16x8*)(q + base);
  bf16x8 kv8 = *(const bf16x8*)(k + base);
  float qf[8], kf[8], qss = 0.f, kss = 0.f;
#pragma unroll
  for (int i = 0; i < 8; ++i) {
    qf[i] = b2f(qv8[i]); kf[i] = b2f(kv8[i]);
    qss = fmaf(qf[i], qf[i], qss); kss = fmaf(kf[i], kf[i], kss);
  }
#pragma unroll
  for (int o = 1; o < 8; o <<= 1) { qss += __shfl_xor(qss, o); kss += __shfl_xor(kss, o); }
  float qr = rsqrtf(qss), kr = rsqrtf(kss);
  float qs = 0.f, ks = 0.f;
#pragma unroll
  for (int i = 0; i < 8; ++i) {
    qf[i] *= qr; kf[i] *= kr;
    qv8[i] = f2b(qf[i]); kv8[i] = f2b(kf[i]);
    qs += qf[i]; ks += kf[i];
  }
  *(bf16x8*)(q + base) = qv8;
  *(bf16x8*)(k + base) = kv8;
#pragma unroll
  for (int o = 1; o < 64; o <<= 1) { qs += __shfl_xor(qs, o); ks += __shfl_xor(ks, o); }
  __shared__ float sq[4], sk[4];
  int wid = tid >> 6, lane = tid & 63;
  if (lane == 0) { sq[wid] = qs; sk[wid] = ks; }
  __syncthreads();
  if (tid == 0) {
    partials[blockIdx.x]          = sq[0] + sq[1] + sq[2] + sq[3];
    partials[NBLKNM + blockIdx.x] = sk[0] + sk[1] + sk[2] + sk[3];
  }
}

__global__ __launch_bounds__(256) void mean_reduce_kernel(
    const float* __restrict__ partials, float* __restrict__ means)
{
  float sq = 0.f, sk = 0.f;
  for (int i = threadIdx.x; i < NBLKNM; i += 256) {
    sq += partials[i]; sk += partials[NBLKNM + i];
  }
#pragma unroll
  for (int o = 32; o; o >>= 1) { sq += __shfl_xor(sq, o); sk += __shfl_xor(sk, o); }
  __shared__ float s[8];
  int wid = threadIdx.x >> 6, lane = threadIdx.x & 63;
  if (lane == 0) { s[wid] = sq; s[4 + wid] = sk; }
  __syncthreads();
  if (threadIdx.x == 0) {
    means[0] = (s[0] + s[1] + s[2] + s[3]) / 12582912.f;
    means[1] = (s[4] + s[5] + s[6] + s[7]) / 12582912.f;
  }
}

// ---------------------------------------------------------------------------
// attn partials over 128-token chunks; deterministic tree reduce after.
// ---------------------------------------------------------------------------
__global__ __launch_bounds__(256) void attn_part_kernel(
    const short* __restrict__ k, const short* __restrict__ v,
    const float* __restrict__ means, float* __restrict__ part)
{
  int bh = blockIdx.x / NCH;
  int ch = blockIdx.x % NCH;
  int dd = threadIdx.x >> 2;
  int e0 = (threadIdx.x & 3) << 4;
  float mk = means[1];
  float acc[16];
#pragma unroll
  for (int i = 0; i < 16; ++i) acc[i] = 0.f;
  const short* kb = k + ((size_t)bh << 16) + (ch << 13);
  const short* vb = v + ((size_t)bh << 16) + (ch << 13);
  for (int n = 0; n < N_TOK / NCH; ++n) {
    bool on = (b2f(kb[(n << 6) + dd]) - mk) > 0.f;
    if (on) {
      const short* vp = vb + (n << 6) + e0;
      bf16x8 v0 = *(const bf16x8*)(vp);
      bf16x8 v1 = *(const bf16x8*)(vp + 8);
#pragma unroll
      for (int i = 0; i < 8; ++i) { acc[i] += b2f(v0[i]); acc[8 + i] += b2f(v1[i]); }
    }
  }
  float* pp = part + ((size_t)blockIdx.x << 12) + dd * 64 + e0;
#pragma unroll
  for (int i = 0; i < 16; ++i) pp[i] = acc[i];
}

__global__ __launch_bounds__(256) void attn_reduce_kernel(
    const float* __restrict__ part, float* __restrict__ attn)
{
  int idx = blockIdx.x * 256 + threadIdx.x;   // over 192*4096
  int bh  = idx >> 12;
  int off = idx & 4095;
  float s = 0.f;
#pragma unroll
  for (int c = 0; c < NCH; ++c)
    s += part[(((size_t)bh * NCH + c) << 12) + off];
  attn[idx] = s;
}

// ---------------------------------------------------------------------------
// out rows: o = 0.5 v + (1/pi) qbits.attn ; normalize ; + depthwise conv.
// Block = 128 rows of one (b,h); attn column hoisted to 64 VGPRs; v window
// staged in LDS for the conv taps.
// ---------------------------------------------------------------------------
__global__ __launch_bounds__(256) void out_kernel(
    const short* __restrict__ q, const short* __restrict__ v,
    const float* __restrict__ attn, const float* __restrict__ means,
    const float* __restrict__ wd, short* __restrict__ mid)
{
  __shared__ short v_s[136 * 64];     // rows n0-4 .. n0+131
  int tid = threadIdx.x, lane = tid & 63, wid = tid >> 6;
  int bh = blockIdx.x >> 3;
  int n0 = (blockIdx.x & 7) << 7;
  int h  = bh % 12;
  int b  = bh / 12;

  const short* vb = v + ((size_t)bh << 16);
  for (int i = tid; i < 2176; i += 256) {
    int r = i >> 4, c = (i & 15) << 2;
    int nn = n0 - 4 + r;
    s16x4 val = {0, 0, 0, 0};
    if (nn >= 0 && nn < N_TOK) val = *(const s16x4*)(vb + (nn << 6) + c);
    *(s16x4*)(v_s + (i << 2)) = val;
  }

  const float* ag = attn + ((size_t)bh << 12) + lane;
  float col[64];
#pragma unroll
  for (int dd = 0; dd < 64; ++dd) col[dd] = ag[dd << 6];

  float mq = means[0];
  float wc[9];
#pragma unroll
  for (int j = 0; j < 9; ++j) wc[j] = wd[h * 9 + j];
  __syncthreads();

  const short* qb = q + ((size_t)bh << 16);
  for (int t = 0; t < 32; ++t) {
    int ln = (wid << 5) + t;
    int n  = n0 + ln;
    float qv = b2f(qb[(n << 6) + lane]);
    unsigned long long qmask = __ballot((qv - mq) > 0.f);
    float acc = 0.f;
#pragma unroll
    for (int dd = 0; dd < 64; ++dd) {
      float bitf = (float)((unsigned)((qmask >> dd) & 1ull));
      acc = fmaf(bitf, col[dd], acc);
    }
    float vv = b2f(v_s[((ln + 4) << 6) + lane]);
    float o = 0.5f * vv + acc * 0.3183098861837907f;
    float ss = o * o;
#pragma unroll
    for (int off = 32; off; off >>= 1) ss += __shfl_xor(ss, off);
    o *= rsqrtf(ss);
#pragma unroll
    for (int j = 0; j < 9; ++j)
      o += wc[j] * b2f(v_s[((ln + j) << 6) + lane]);
    mid[(size_t)((b << 10) | n) * 768 + (h << 6) + lane] = f2b(o);
  }
}

extern "C" void kernel_launch(void* const* d_in, const int* in_sizes, int n_in,
                              void* d_out, int out_size, void* d_ws, size_t ws_size,
                              hipStream_t stream) {
  (void)in_sizes; (void)n_in; (void)out_size; (void)ws_size;
  const float* x       = (const float*)d_in[0];
  const float* w_qkv   = (const float*)d_in[3];
  const float* w_dconv = (const float*)d_in[4];
  const float* w_proj  = (const float*)d_in[5];
  const float* b_proj  = (const float*)d_in[6];

  // ---- workspace layout (phase-safe aliasing), ~130.5 MB ----
  char* ws = (char*)d_ws;
  short* qbuf = (short*)ws;                         // 3*QKV_E shorts
  short* kbuf = qbuf + QKV_E;
  short* vbuf = kbuf + QKV_E;
  char*  r2   = ws + (size_t)3 * QKV_E * 2;         // 3.54 MB region:
  short* wqkvT    = (short*)r2;                     //   phases 0-1
  float* attn     = (float*)r2;                     //   phases 5-6 (3.15 MB)
  float* partials = (float*)(r2 + 3145728);         //   phases 2-3 (48 KB)
  short* mid  = (short*)(r2 + 3538944);             // 25.2 MB
  char*  r4   = (char*)mid + (size_t)16384 * 768 * 2;
  short* xb        = (short*)r4;                    // 25.2 MB, phases 0-1
  float* attn_part = (float*)r4;                    //   reused phases 4-5
  short* wprojT = (short*)(r4 + (size_t)QKV_E * 2); // 1.18 MB, phases 0,7
  float* means  = (float*)((char*)wprojT + (size_t)768 * 768 * 2);

  // 0) convert x -> bf16; transpose+convert weights
  cvt_bf16_kernel<<<QKV_E / 8 / 256, 256, 0, stream>>>(x, xb, QKV_E / 8);
  dim3 gt1(2304 / 64, 768 / 64);
  transpose_cvt_kernel<<<gt1, 256, 0, stream>>>(w_qkv, wqkvT, 768, 2304);
  dim3 gt2(768 / 64, 768 / 64);
  transpose_cvt_kernel<<<gt2, 256, 0, stream>>>(w_proj, wprojT, 768, 768);

  // 1) QKV GEMM: xb[16384,768] @ wqkvT[2304,768]^T -> q,k,v bf16 [B,h,N,d]
  gemm128<0><<<(2304 / 128) * (16384 / 128), 256, 0, stream>>>(
      xb, wqkvT, 2304, 768, 18, qbuf, nullptr, nullptr);

  // 2-3) normalize q,k + global means
  norm_mean_kernel<<<NBLKNM, 256, 0, stream>>>(qbuf, kbuf, partials);
  mean_reduce_kernel<<<1, 256, 0, stream>>>(partials, means);

  // 4-5) attn = binarized(k)^T v, chunked + reduced
  attn_part_kernel<<<B_ * HEADS_ * NCH, 256, 0, stream>>>(kbuf, vbuf, means, attn_part);
  attn_reduce_kernel<<<B_ * HEADS_ * 4096 / 256, 256, 0, stream>>>(attn_part, attn);

  // 6) out rows -> mid bf16 [B,N,768]
  out_kernel<<<ROWS_ / 128, 256, 0, stream>>>(qbuf, vbuf, attn, means, w_dconv, mid);

  // 7) projection: mid @ wprojT^T + b_proj -> d_out f32
  gemm128<1><<<(768 / 128) * (16384 / 128), 256, 0, stream>>>(
      mid, wprojT, 768, 768, 6, nullptr, (float*)d_out, b_proj);
}

// Round 6
// 320.023 us; speedup vs baseline: 4.1659x; 1.1888x over previous
//
#include <hip/hip_runtime.h>
#include <hip/hip_bf16.h>

#define B_      16
#define N_TOK   1024
#define DIM_    768
#define HEADS_  12
#define DHEAD   64
#define KRES_   9

#define QKV_E   (12582912)           // B*HEADS*N*DHEAD
#define ROWS_   (B_*HEADS_*N_TOK)    // 196608
#define NCH     8                    // attn n-chunks per (b,h)
#define NBLKNM  6144                 // norm_mean blocks (32 rows each)

typedef __attribute__((ext_vector_type(8))) short bf16x8;
typedef __attribute__((ext_vector_type(4))) short s16x4;
typedef __attribute__((ext_vector_type(4))) float f32x4;

__device__ inline short f2b(float f) {
  unsigned u = __builtin_bit_cast(unsigned, f);
  u += 0x7fff + ((u >> 16) & 1);   // round-to-nearest-even
  return (short)(u >> 16);
}
__device__ inline float b2f(short s) {
  unsigned u = ((unsigned)(unsigned short)s) << 16;
  return __builtin_bit_cast(float, u);
}

__device__ inline void gload16(const short* g, short* l) {
  __builtin_amdgcn_global_load_lds(
      (const __attribute__((address_space(1))) void*)g,
      (__attribute__((address_space(3))) void*)l, 16, 0, 0);
}

// ---------------------------------------------------------------------------
// x (f32) -> bf16, vectorized 8/thread
// ---------------------------------------------------------------------------
__global__ __launch_bounds__(256) void cvt_bf16_kernel(
    const float* __restrict__ in, short* __restrict__ out, int n8)
{
  int i = blockIdx.x * 256 + threadIdx.x;
  if (i >= n8) return;
  float4 a = ((const float4*)in)[2 * i];
  float4 b = ((const float4*)in)[2 * i + 1];
  bf16x8 v;
  v[0]=f2b(a.x); v[1]=f2b(a.y); v[2]=f2b(a.z); v[3]=f2b(a.w);
  v[4]=f2b(b.x); v[5]=f2b(b.y); v[6]=f2b(b.z); v[7]=f2b(b.w);
  ((bf16x8*)out)[i] = v;
}

// ---------------------------------------------------------------------------
// f32 [R][C] -> bf16 [C][R] (64x64 LDS tiles). R,C multiples of 64.
// ---------------------------------------------------------------------------
__global__ __launch_bounds__(256) void transpose_cvt_kernel(
    const float* __restrict__ in, short* __restrict__ out, int R, int C)
{
  __shared__ short t[64][65];
  int c0 = blockIdx.x * 64, r0 = blockIdx.y * 64;
#pragma unroll
  for (int p = 0; p < 4; ++p) {
    int r = (threadIdx.x >> 4) + p * 16;
    int c = (threadIdx.x & 15) * 4;
    float4 v = *(const float4*)(in + (size_t)(r0 + r) * C + c0 + c);
    t[c][r] = f2b(v.x); t[c + 1][r] = f2b(v.y);
    t[c + 2][r] = f2b(v.z); t[c + 3][r] = f2b(v.w);
  }
  __syncthreads();
#pragma unroll
  for (int p = 0; p < 4; ++p) {
    int oc = (threadIdx.x >> 4) + p * 16;
    int orr = (threadIdx.x & 15) * 4;
    s16x4 v = { t[oc][orr], t[oc][orr + 1], t[oc][orr + 2], t[oc][orr + 3] };
    *(s16x4*)(out + (size_t)(c0 + oc) * R + r0 + orr) = v;
  }
}

// ---------------------------------------------------------------------------
// m97-structure GEMM (round-4 verified K-loop): C = A[M,K] * BT[N,K]^T, bf16.
// 128x128 tile, 256 thr / 4 waves, BK=32, SINGLE-buffered linear LDS,
// plain 2-barrier loop (explicit dbuf regressed: -31% via occupancy loss).
// 1-D grid + XCD-chunked bijective swizzle (kept: FETCH 120 -> 85 MB).
// MODE 0: scatter bf16 -> q/k/v [B,h,N,d];  MODE 1: f32 + bias -> out.
// ---------------------------------------------------------------------------
template<int MODE>
__global__ __launch_bounds__(256) void gemm128(
    const short* __restrict__ A, const short* __restrict__ BT,
    int N, int K, int nxblk,
    short* __restrict__ qkv_out, float* __restrict__ proj_out,
    const float* __restrict__ bias)
{
  __shared__ short As[128 * 32];
  __shared__ short Bs[128 * 32];

  const int tid  = threadIdx.x;
  const int lane = tid & 63;
  const int wid  = tid >> 6;
  const int wr   = wid >> 1, wc = wid & 1;

  // XCD swizzle: nwg%8==0 -> each XCD owns a contiguous col-fastest chunk
  const int nwg = (int)gridDim.x;
  const int cpx = nwg >> 3;
  const int swz = (blockIdx.x & 7) * cpx + (blockIdx.x >> 3);
  const int bx  = swz % nxblk, by = swz / nxblk;
  const int rowBase = by << 7;
  const int colBase = bx << 7;

  const int fr  = lane & 15;
  const int fko = (lane >> 4) << 3;

  const int srow = tid >> 2;          // staging row 0..63 (per half)
  const int skg  = (tid & 3) << 3;    // staging k offset (elems)

  const short* Ap  = A  + (size_t)(rowBase + srow) * K + skg;
  const short* Bp  = BT + (size_t)(colBase + srow) * K + skg;
  const short* Ap2 = Ap + (size_t)64 * K;
  const short* Bp2 = Bp + (size_t)64 * K;
  short* dA  = As + tid * 8;          // linear dest rule: byte off = 16*tid
  short* dA2 = As + 2048 + tid * 8;
  short* dB  = Bs + tid * 8;
  short* dB2 = Bs + 2048 + tid * 8;

  f32x4 acc[4][4];
#pragma unroll
  for (int i = 0; i < 4; ++i)
#pragma unroll
    for (int j = 0; j < 4; ++j) acc[i][j] = f32x4{0.f, 0.f, 0.f, 0.f};

  for (int k0 = 0; k0 < K; k0 += 32) {
    __syncthreads();
    gload16(Ap  + k0, dA);
    gload16(Ap2 + k0, dA2);
    gload16(Bp  + k0, dB);
    gload16(Bp2 + k0, dB2);
    __syncthreads();

    bf16x8 a[4], b[4];
#pragma unroll
    for (int i = 0; i < 4; ++i)
      a[i] = *(const bf16x8*)(As + (wr * 64 + i * 16 + fr) * 32 + fko);
#pragma unroll
    for (int j = 0; j < 4; ++j)
      b[j] = *(const bf16x8*)(Bs + (wc * 64 + j * 16 + fr) * 32 + fko);
#pragma unroll
    for (int i = 0; i < 4; ++i)
#pragma unroll
      for (int j = 0; j < 4; ++j)
        acc[i][j] = __builtin_amdgcn_mfma_f32_16x16x32_bf16(a[i], b[j], acc[i][j], 0, 0, 0);
  }

  // ---- epilogue: D frag layout col = lane&15, row = (lane>>4)*4 + e ----
  if (MODE == 0) {
    const int b  = rowBase >> 10;                      // tile stays in one b
    const int n0 = (rowBase & 1023) + wr * 64 + ((lane >> 4) << 2);
#pragma unroll
    for (int j = 0; j < 4; ++j) {
      int gc = colBase + wc * 64 + j * 16 + fr;
      int part = (gc >= 1536) ? 2 : (gc >= 768 ? 1 : 0);
      int rem  = gc - part * 768;
      int hd = rem >> 6, dd = rem & 63;
      size_t cbase = (size_t)part * QKV_E
                   + ((size_t)(b * 12 + hd) << 16) + dd;
#pragma unroll
      for (int i = 0; i < 4; ++i)
#pragma unroll
        for (int e = 0; e < 4; ++e)
          qkv_out[cbase + ((size_t)(n0 + i * 16 + e) << 6)] = f2b(acc[i][j][e]);
    }
  } else {
    const int gr0 = rowBase + wr * 64 + ((lane >> 4) << 2);
#pragma unroll
    for (int j = 0; j < 4; ++j) {
      int gc = colBase + wc * 64 + j * 16 + fr;
      float bj = bias[gc];
#pragma unroll
      for (int i = 0; i < 4; ++i)
#pragma unroll
        for (int e = 0; e < 4; ++e)
          proj_out[(size_t)(gr0 + i * 16 + e) * N + gc] = acc[i][j][e] + bj;
    }
  }
}

// ---------------------------------------------------------------------------
// Normalize q,k rows in place, vectorized: thread owns 8 elems; row = 8
// lanes; block = 32 rows. Per-block sums for the global means.
// ---------------------------------------------------------------------------
__global__ __launch_bounds__(256) void norm_mean_kernel(
    short* __restrict__ q, short* __restrict__ k, float* __restrict__ partials)
{
  int tid = threadIdx.x;
  size_t base = (size_t)blockIdx.x * 2048 + (size_t)tid * 8;
  bf16x8 qv8 = *(const bf16x8*)(q + base);
  bf16x8 kv8 = *(const bf16x8*)(k + base);
  float qf[8], kf[8], qss = 0.f, kss = 0.f;
#pragma unroll
  for (int i = 0; i < 8; ++i) {
    qf[i] = b2f(qv8[i]); kf[i] = b2f(kv8[i]);
    qss = fmaf(qf[i], qf[i], qss); kss = fmaf(kf[i], kf[i], kss);
  }
#pragma unroll
  for (int o = 1; o < 8; o <<= 1) { qss += __shfl_xor(qss, o); kss += __shfl_xor(kss, o); }
  float qr = rsqrtf(qss), kr = rsqrtf(kss);
  float qs = 0.f, ks = 0.f;
#pragma unroll
  for (int i = 0; i < 8; ++i) {
    qf[i] *= qr; kf[i] *= kr;
    qv8[i] = f2b(qf[i]); kv8[i] = f2b(kf[i]);
    qs += qf[i]; ks += kf[i];
  }
  *(bf16x8*)(q + base) = qv8;
  *(bf16x8*)(k + base) = kv8;
#pragma unroll
  for (int o = 1; o < 64; o <<= 1) { qs += __shfl_xor(qs, o); ks += __shfl_xor(ks, o); }
  __shared__ float sq[4], sk[4];
  int wid = tid >> 6, lane = tid & 63;
  if (lane == 0) { sq[wid] = qs; sk[wid] = ks; }
  __syncthreads();
  if (tid == 0) {
    partials[blockIdx.x]          = sq[0] + sq[1] + sq[2] + sq[3];
    partials[NBLKNM + blockIdx.x] = sk[0] + sk[1] + sk[2] + sk[3];
  }
}

__global__ __launch_bounds__(256) void mean_reduce_kernel(
    const float* __restrict__ partials, float* __restrict__ means)
{
  float sq = 0.f, sk = 0.f;
  for (int i = threadIdx.x; i < NBLKNM; i += 256) {
    sq += partials[i]; sk += partials[NBLKNM + i];
  }
#pragma unroll
  for (int o = 32; o; o >>= 1) { sq += __shfl_xor(sq, o); sk += __shfl_xor(sk, o); }
  __shared__ float s[8];
  int wid = threadIdx.x >> 6, lane = threadIdx.x & 63;
  if (lane == 0) { s[wid] = sq; s[4 + wid] = sk; }
  __syncthreads();
  if (threadIdx.x == 0) {
    means[0] = (s[0] + s[1] + s[2] + s[3]) / 12582912.f;
    means[1] = (s[4] + s[5] + s[6] + s[7]) / 12582912.f;
  }
}

// ---------------------------------------------------------------------------
// attn partials over 128-token chunks; deterministic tree reduce after.
// ---------------------------------------------------------------------------
__global__ __launch_bounds__(256) void attn_part_kernel(
    const short* __restrict__ k, const short* __restrict__ v,
    const float* __restrict__ means, float* __restrict__ part)
{
  int bh = blockIdx.x / NCH;
  int ch = blockIdx.x % NCH;
  int dd = threadIdx.x >> 2;
  int e0 = (threadIdx.x & 3) << 4;
  float mk = means[1];
  float acc[16];
#pragma unroll
  for (int i = 0; i < 16; ++i) acc[i] = 0.f;
  const short* kb = k + ((size_t)bh << 16) + (ch << 13);
  const short* vb = v + ((size_t)bh << 16) + (ch << 13);
  for (int n = 0; n < N_TOK / NCH; ++n) {
    bool on = (b2f(kb[(n << 6) + dd]) - mk) > 0.f;
    if (on) {
      const short* vp = vb + (n << 6) + e0;
      bf16x8 v0 = *(const bf16x8*)(vp);
      bf16x8 v1 = *(const bf16x8*)(vp + 8);
#pragma unroll
      for (int i = 0; i < 8; ++i) { acc[i] += b2f(v0[i]); acc[8 + i] += b2f(v1[i]); }
    }
  }
  float* pp = part + ((size_t)blockIdx.x << 12) + dd * 64 + e0;
#pragma unroll
  for (int i = 0; i < 16; ++i) pp[i] = acc[i];
}

__global__ __launch_bounds__(256) void attn_reduce_kernel(
    const float* __restrict__ part, float* __restrict__ attn)
{
  int idx = blockIdx.x * 256 + threadIdx.x;   // over 192*4096
  int bh  = idx >> 12;
  int off = idx & 4095;
  float s = 0.f;
#pragma unroll
  for (int c = 0; c < NCH; ++c)
    s += part[(((size_t)bh * NCH + c) << 12) + off];
  attn[idx] = s;
}

// ---------------------------------------------------------------------------
// out rows: o = 0.5 v + (1/pi) qbits.attn ; normalize ; + depthwise conv.
// Block = 128 rows of one (b,h); attn column hoisted to 64 VGPRs; v window
// staged in LDS for the conv taps.
// ---------------------------------------------------------------------------
__global__ __launch_bounds__(256) void out_kernel(
    const short* __restrict__ q, const short* __restrict__ v,
    const float* __restrict__ attn, const float* __restrict__ means,
    const float* __restrict__ wd, short* __restrict__ mid)
{
  __shared__ short v_s[136 * 64];     // rows n0-4 .. n0+131
  int tid = threadIdx.x, lane = tid & 63, wid = tid >> 6;
  int bh = blockIdx.x >> 3;
  int n0 = (blockIdx.x & 7) << 7;
  int h  = bh % 12;
  int b  = bh / 12;

  const short* vb = v + ((size_t)bh << 16);
  for (int i = tid; i < 2176; i += 256) {
    int r = i >> 4, c = (i & 15) << 2;
    int nn = n0 - 4 + r;
    s16x4 val = {0, 0, 0, 0};
    if (nn >= 0 && nn < N_TOK) val = *(const s16x4*)(vb + (nn << 6) + c);
    *(s16x4*)(v_s + (i << 2)) = val;
  }

  const float* ag = attn + ((size_t)bh << 12) + lane;
  float col[64];
#pragma unroll
  for (int dd = 0; dd < 64; ++dd) col[dd] = ag[dd << 6];

  float mq = means[0];
  float wc[9];
#pragma unroll
  for (int j = 0; j < 9; ++j) wc[j] = wd[h * 9 + j];
  __syncthreads();

  const short* qb = q + ((size_t)bh << 16);
  for (int t = 0; t < 32; ++t) {
    int ln = (wid << 5) + t;
    int n  = n0 + ln;
    float qv = b2f(qb[(n << 6) + lane]);
    unsigned long long qmask = __ballot((qv - mq) > 0.f);
    float acc = 0.f;
#pragma unroll
    for (int dd = 0; dd < 64; ++dd) {
      float bitf = (float)((unsigned)((qmask >> dd) & 1ull));
      acc = fmaf(bitf, col[dd], acc);
    }
    float vv = b2f(v_s[((ln + 4) << 6) + lane]);
    float o = 0.5f * vv + acc * 0.3183098861837907f;
    float ss = o * o;
#pragma unroll
    for (int off = 32; off; off >>= 1) ss += __shfl_xor(ss, off);
    o *= rsqrtf(ss);
#pragma unroll
    for (int j = 0; j < 9; ++j)
      o += wc[j] * b2f(v_s[((ln + j) << 6) + lane]);
    mid[(size_t)((b << 10) | n) * 768 + (h << 6) + lane] = f2b(o);
  }
}

extern "C" void kernel_launch(void* const* d_in, const int* in_sizes, int n_in,
                              void* d_out, int out_size, void* d_ws, size_t ws_size,
                              hipStream_t stream) {
  (void)in_sizes; (void)n_in; (void)out_size; (void)ws_size;
  const float* x       = (const float*)d_in[0];
  const float* w_qkv   = (const float*)d_in[3];
  const float* w_dconv = (const float*)d_in[4];
  const float* w_proj  = (const float*)d_in[5];
  const float* b_proj  = (const float*)d_in[6];

  // ---- workspace layout (phase-safe aliasing), ~130.5 MB ----
  char* ws = (char*)d_ws;
  short* qbuf = (short*)ws;                         // 3*QKV_E shorts
  short* kbuf = qbuf + QKV_E;
  short* vbuf = kbuf + QKV_E;
  char*  r2   = ws + (size_t)3 * QKV_E * 2;         // 3.54 MB region:
  short* wqkvT    = (short*)r2;                     //   phases 0-1
  float* attn     = (float*)r2;                     //   phases 5-6 (3.15 MB)
  float* partials = (float*)(r2 + 3145728);         //   phases 2-3 (48 KB)
  short* mid  = (short*)(r2 + 3538944);             // 25.2 MB
  char*  r4   = (char*)mid + (size_t)16384 * 768 * 2;
  short* xb        = (short*)r4;                    // 25.2 MB, phases 0-1
  float* attn_part = (float*)r4;                    //   reused phases 4-5
  short* wprojT = (short*)(r4 + (size_t)QKV_E * 2); // 1.18 MB, phases 0,7
  float* means  = (float*)((char*)wprojT + (size_t)768 * 768 * 2);

  // 0) convert x -> bf16; transpose+convert weights
  cvt_bf16_kernel<<<QKV_E / 8 / 256, 256, 0, stream>>>(x, xb, QKV_E / 8);
  dim3 gt1(2304 / 64, 768 / 64);
  transpose_cvt_kernel<<<gt1, 256, 0, stream>>>(w_qkv, wqkvT, 768, 2304);
  dim3 gt2(768 / 64, 768 / 64);
  transpose_cvt_kernel<<<gt2, 256, 0, stream>>>(w_proj, wprojT, 768, 768);

  // 1) QKV GEMM: xb[16384,768] @ wqkvT[2304,768]^T -> q,k,v bf16 [B,h,N,d]
  gemm128<0><<<(2304 / 128) * (16384 / 128), 256, 0, stream>>>(
      xb, wqkvT, 2304, 768, 18, qbuf, nullptr, nullptr);

  // 2-3) normalize q,k + global means
  norm_mean_kernel<<<NBLKNM, 256, 0, stream>>>(qbuf, kbuf, partials);
  mean_reduce_kernel<<<1, 256, 0, stream>>>(partials, means);

  // 4-5) attn = binarized(k)^T v, chunked + reduced
  attn_part_kernel<<<B_ * HEADS_ * NCH, 256, 0, stream>>>(kbuf, vbuf, means, attn_part);
  attn_reduce_kernel<<<B_ * HEADS_ * 4096 / 256, 256, 0, stream>>>(attn_part, attn);

  // 6) out rows -> mid bf16 [B,N,768]
  out_kernel<<<ROWS_ / 128, 256, 0, stream>>>(qbuf, vbuf, attn, means, w_dconv, mid);

  // 7) projection: mid @ wprojT^T + b_proj -> d_out f32
  gemm128<1><<<(768 / 128) * (16384 / 128), 256, 0, stream>>>(
      mid, wprojT, 768, 768, 6, nullptr, (float*)d_out, b_proj);
}

// Round 8
// 285.808 us; speedup vs baseline: 4.6646x; 1.1197x over previous
//
#include <hip/hip_runtime.h>
#include <hip/hip_bf16.h>

#define B_      16
#define N_TOK   1024
#define DIM_    768
#define HEADS_  12
#define DHEAD   64
#define KRES_   9

#define QKV_E   (12582912)           // B*HEADS*N*DHEAD
#define ROWS_   (B_*HEADS_*N_TOK)    // 196608
#define ACH     4                    // attn n-chunks per (b,h)

typedef __attribute__((ext_vector_type(8))) short bf16x8;
typedef __attribute__((ext_vector_type(4))) short s16x4;
typedef __attribute__((ext_vector_type(4))) float f32x4;

__device__ inline short f2b(float f) {
  unsigned u = __builtin_bit_cast(unsigned, f);
  u += 0x7fff + ((u >> 16) & 1);   // round-to-nearest-even
  return (short)(u >> 16);
}
__device__ inline float b2f(short s) {
  unsigned u = ((unsigned)(unsigned short)s) << 16;
  return __builtin_bit_cast(float, u);
}

__device__ inline void gload16(const short* g, short* l) {
  __builtin_amdgcn_global_load_lds(
      (const __attribute__((address_space(1))) void*)g,
      (__attribute__((address_space(3))) void*)l, 16, 0, 0);
}

// ---------------------------------------------------------------------------
// x (f32) -> bf16, vectorized 8/thread
// ---------------------------------------------------------------------------
__global__ __launch_bounds__(256) void cvt_bf16_kernel(
    const float* __restrict__ in, short* __restrict__ out, int n8)
{
  int i = blockIdx.x * 256 + threadIdx.x;
  if (i >= n8) return;
  float4 a = ((const float4*)in)[2 * i];
  float4 b = ((const float4*)in)[2 * i + 1];
  bf16x8 v;
  v[0]=f2b(a.x); v[1]=f2b(a.y); v[2]=f2b(a.z); v[3]=f2b(a.w);
  v[4]=f2b(b.x); v[5]=f2b(b.y); v[6]=f2b(b.z); v[7]=f2b(b.w);
  ((bf16x8*)out)[i] = v;
}

// ---------------------------------------------------------------------------
// f32 [R][C] -> bf16 [C][R] (64x64 LDS tiles). R,C multiples of 64.
// ---------------------------------------------------------------------------
__global__ __launch_bounds__(256) void transpose_cvt_kernel(
    const float* __restrict__ in, short* __restrict__ out, int R, int C)
{
  __shared__ short t[64][65];
  int c0 = blockIdx.x * 64, r0 = blockIdx.y * 64;
#pragma unroll
  for (int p = 0; p < 4; ++p) {
    int r = (threadIdx.x >> 4) + p * 16;
    int c = (threadIdx.x & 15) * 4;
    float4 v = *(const float4*)(in + (size_t)(r0 + r) * C + c0 + c);
    t[c][r] = f2b(v.x); t[c + 1][r] = f2b(v.y);
    t[c + 2][r] = f2b(v.z); t[c + 3][r] = f2b(v.w);
  }
  __syncthreads();
#pragma unroll
  for (int p = 0; p < 4; ++p) {
    int oc = (threadIdx.x >> 4) + p * 16;
    int orr = (threadIdx.x & 15) * 4;
    s16x4 v = { t[oc][orr], t[oc][orr + 1], t[oc][orr + 2], t[oc][orr + 3] };
    *(s16x4*)(out + (size_t)(c0 + oc) * R + r0 + orr) = v;
  }
}

// ---------------------------------------------------------------------------
// m97-structure GEMM: C = A[M,K] * BT[N,K]^T, bf16. 128x128 tile, 4 waves,
// BK=32, single-buffered linear LDS, 2-barrier loop, XCD-chunked swizzle.
// MODE 0: fused epilogue — per-row L2-normalize q/k heads in-register
//         (row = 4 j-frags + shfl_xor over the 16-lane col group), emit
//         per-block sums of normalized values for the global means, then
//         scatter bf16 -> q/k/v [B,h,N,d].  v heads stored unnormalized.
//         NOTE: partials must NOT alias any buffer this kernel reads
//         (round-7 NaN: partials overlapped wqkvT -> race -> NaN bf16s).
// MODE 1: f32 + bias -> out.
// ---------------------------------------------------------------------------
template<int MODE>
__global__ __launch_bounds__(256) void gemm128(
    const short* __restrict__ A, const short* __restrict__ BT,
    int N, int K, int nxblk,
    short* __restrict__ qkv_out, float* __restrict__ proj_out,
    const float* __restrict__ bias, float* __restrict__ partials)
{
  __shared__ short As[128 * 32];
  __shared__ short Bs[128 * 32];
  __shared__ float sred[4];

  const int tid  = threadIdx.x;
  const int lane = tid & 63;
  const int wid  = tid >> 6;
  const int wr   = wid >> 1, wc = wid & 1;

  // XCD swizzle: nwg%8==0 -> each XCD owns a contiguous col-fastest chunk
  const int nwg = (int)gridDim.x;
  const int cpx = nwg >> 3;
  const int swz = (blockIdx.x & 7) * cpx + (blockIdx.x >> 3);
  const int bx  = swz % nxblk, by = swz / nxblk;
  const int rowBase = by << 7;
  const int colBase = bx << 7;

  const int fr  = lane & 15;
  const int fko = (lane >> 4) << 3;

  const int srow = tid >> 2;
  const int skg  = (tid & 3) << 3;

  const short* Ap  = A  + (size_t)(rowBase + srow) * K + skg;
  const short* Bp  = BT + (size_t)(colBase + srow) * K + skg;
  const short* Ap2 = Ap + (size_t)64 * K;
  const short* Bp2 = Bp + (size_t)64 * K;
  short* dA  = As + tid * 8;          // linear dest rule: byte off = 16*tid
  short* dA2 = As + 2048 + tid * 8;
  short* dB  = Bs + tid * 8;
  short* dB2 = Bs + 2048 + tid * 8;

  f32x4 acc[4][4];
#pragma unroll
  for (int i = 0; i < 4; ++i)
#pragma unroll
    for (int j = 0; j < 4; ++j) acc[i][j] = f32x4{0.f, 0.f, 0.f, 0.f};

  for (int k0 = 0; k0 < K; k0 += 32) {
    __syncthreads();
    gload16(Ap  + k0, dA);
    gload16(Ap2 + k0, dA2);
    gload16(Bp  + k0, dB);
    gload16(Bp2 + k0, dB2);
    __syncthreads();

    bf16x8 a[4], b[4];
#pragma unroll
    for (int i = 0; i < 4; ++i)
      a[i] = *(const bf16x8*)(As + (wr * 64 + i * 16 + fr) * 32 + fko);
#pragma unroll
    for (int j = 0; j < 4; ++j)
      b[j] = *(const bf16x8*)(Bs + (wc * 64 + j * 16 + fr) * 32 + fko);
#pragma unroll
    for (int i = 0; i < 4; ++i)
#pragma unroll
      for (int j = 0; j < 4; ++j)
        acc[i][j] = __builtin_amdgcn_mfma_f32_16x16x32_bf16(a[i], b[j], acc[i][j], 0, 0, 0);
  }

  // ---- epilogue: D frag layout col = lane&15, row = (lane>>4)*4 + e ----
  if (MODE == 0) {
    const int b    = rowBase >> 10;                   // tile stays in one b
    const int n0   = (rowBase & 1023) + wr * 64 + ((lane >> 4) << 2);
    const int part = colBase / 768;                   // block-uniform (768%128==0)
    const int hd   = ((colBase - part * 768) >> 6) + wc;
    float psum = 0.f;

    if (part < 2) {
      // row sum-of-squares: sum over j-frags, then over the 16-lane col group
      float ss[4][4];
#pragma unroll
      for (int i = 0; i < 4; ++i)
#pragma unroll
        for (int e = 0; e < 4; ++e) {
          float s = 0.f;
#pragma unroll
          for (int j = 0; j < 4; ++j) s = fmaf(acc[i][j][e], acc[i][j][e], s);
          ss[i][e] = s;
        }
#pragma unroll
      for (int m = 1; m < 16; m <<= 1)
#pragma unroll
        for (int i = 0; i < 4; ++i)
#pragma unroll
          for (int e = 0; e < 4; ++e) ss[i][e] += __shfl_xor(ss[i][e], m);
#pragma unroll
      for (int i = 0; i < 4; ++i)
#pragma unroll
        for (int e = 0; e < 4; ++e) ss[i][e] = rsqrtf(ss[i][e]);
#pragma unroll
      for (int i = 0; i < 4; ++i)
#pragma unroll
        for (int j = 0; j < 4; ++j)
#pragma unroll
          for (int e = 0; e < 4; ++e) {
            acc[i][j][e] *= ss[i][e];
            psum += acc[i][j][e];
          }
    }

    const size_t hbase = (size_t)part * QKV_E + ((size_t)(b * 12 + hd) << 16);
#pragma unroll
    for (int j = 0; j < 4; ++j) {
      const int dd = j * 16 + fr;
#pragma unroll
      for (int i = 0; i < 4; ++i)
#pragma unroll
        for (int e = 0; e < 4; ++e)
          qkv_out[hbase + ((size_t)(n0 + i * 16 + e) << 6) + dd] = f2b(acc[i][j][e]);
    }

    if (part < 2) {          // block-uniform branch: barrier is safe
#pragma unroll
      for (int m = 1; m < 64; m <<= 1) psum += __shfl_xor(psum, m);
      if (lane == 0) sred[wid] = psum;
      __syncthreads();
      if (tid == 0)
        partials[part * 768 + by * 6 + (bx - part * 6)] =
            sred[0] + sred[1] + sred[2] + sred[3];
    }
  } else {
    const int gr0 = rowBase + wr * 64 + ((lane >> 4) << 2);
#pragma unroll
    for (int j = 0; j < 4; ++j) {
      int gc = colBase + wc * 64 + j * 16 + fr;
      float bj = bias[gc];
#pragma unroll
      for (int i = 0; i < 4; ++i)
#pragma unroll
        for (int e = 0; e < 4; ++e)
          proj_out[(size_t)(gr0 + i * 16 + e) * N + gc] = acc[i][j][e] + bj;
    }
  }
}

__global__ __launch_bounds__(256) void mean_reduce_kernel(
    const float* __restrict__ partials, float* __restrict__ means)
{
  float sq = 0.f, sk = 0.f;
  for (int i = threadIdx.x; i < 768; i += 256) {
    sq += partials[i]; sk += partials[768 + i];
  }
#pragma unroll
  for (int o = 32; o; o >>= 1) { sq += __shfl_xor(sq, o); sk += __shfl_xor(sk, o); }
  __shared__ float s[8];
  int wid = threadIdx.x >> 6, lane = threadIdx.x & 63;
  if (lane == 0) { s[wid] = sq; s[4 + wid] = sk; }
  __syncthreads();
  if (threadIdx.x == 0) {
    means[0] = (s[0] + s[1] + s[2] + s[3]) / 12582912.f;
    means[1] = (s[4] + s[5] + s[6] + s[7]) / 12582912.f;
  }
}

// ---------------------------------------------------------------------------
// attn partials via ballot broadcast: block = (bh, 256-token chunk), 4 waves
// x 64 tokens. lane=d for the k read -> one __ballot = binarized row mask
// (wave-uniform); lane=e accumulates acc[64] branchlessly (scalar-select
// fma). Intra-block LDS reduce over the 4 waves; deterministic.
// ---------------------------------------------------------------------------
__global__ __launch_bounds__(256) void attn_part_kernel(
    const short* __restrict__ k, const short* __restrict__ v,
    const float* __restrict__ means, float* __restrict__ part)
{
  __shared__ float red[64][64];
  int tid = threadIdx.x, lane = tid & 63, w = tid >> 6;
  int bh = blockIdx.x >> 2;
  int ch = blockIdx.x & 3;
  float mk = means[1];
  const short* kb = k + ((size_t)bh << 16) + (ch << 14);
  const short* vb = v + ((size_t)bh << 16) + (ch << 14);
  float acc[64];
#pragma unroll
  for (int dd = 0; dd < 64; ++dd) acc[dd] = 0.f;

  const int nbase = w << 6;
  for (int t = 0; t < 64; ++t) {
    int n = nbase + t;
    float kv = b2f(kb[(n << 6) + lane]);
    float vv = b2f(vb[(n << 6) + lane]);
    unsigned long long km = __ballot(kv > mk);
    unsigned lo = (unsigned)km, hi = (unsigned)(km >> 32);
#pragma unroll
    for (int dd = 0; dd < 32; ++dd) {
      float bitf = __builtin_bit_cast(float, ((lo >> dd) & 1u) ? 0x3f800000u : 0u);
      acc[dd] = fmaf(bitf, vv, acc[dd]);
    }
#pragma unroll
    for (int dd = 0; dd < 32; ++dd) {
      float bitf = __builtin_bit_cast(float, ((hi >> dd) & 1u) ? 0x3f800000u : 0u);
      acc[32 + dd] = fmaf(bitf, vv, acc[32 + dd]);
    }
  }

  // cross-wave reduce in LDS (fixed order -> deterministic)
  for (int p = 0; p < 4; ++p) {
    if (w == p) {
#pragma unroll
      for (int dd = 0; dd < 64; ++dd) {
        if (p == 0) red[dd][lane] = acc[dd];
        else        red[dd][lane] += acc[dd];
      }
    }
    __syncthreads();
  }
  float* pp = part + ((size_t)blockIdx.x << 12);
  for (int idx = tid; idx < 4096; idx += 256)
    pp[idx] = red[idx >> 6][idx & 63];
}

__global__ __launch_bounds__(256) void attn_reduce_kernel(
    const float* __restrict__ part, float* __restrict__ attn)
{
  int idx = blockIdx.x * 256 + threadIdx.x;   // over 192*4096
  int bh  = idx >> 12;
  int off = idx & 4095;
  float s = 0.f;
#pragma unroll
  for (int c = 0; c < ACH; ++c)
    s += part[(((size_t)bh * ACH + c) << 12) + off];
  attn[idx] = s;
}

// ---------------------------------------------------------------------------
// out rows: o = 0.5 v + (1/pi) qbits.attn ; normalize ; + depthwise conv.
// Block = 128 rows of one (b,h); attn column hoisted to 64 VGPRs; v window
// staged in LDS for the conv taps.
// ---------------------------------------------------------------------------
__global__ __launch_bounds__(256) void out_kernel(
    const short* __restrict__ q, const short* __restrict__ v,
    const float* __restrict__ attn, const float* __restrict__ means,
    const float* __restrict__ wd, short* __restrict__ mid)
{
  __shared__ short v_s[136 * 64];     // rows n0-4 .. n0+131
  int tid = threadIdx.x, lane = tid & 63, wid = tid >> 6;
  int bh = blockIdx.x >> 3;
  int n0 = (blockIdx.x & 7) << 7;
  int h  = bh % 12;
  int b  = bh / 12;

  const short* vb = v + ((size_t)bh << 16);
  for (int i = tid; i < 2176; i += 256) {
    int r = i >> 4, c = (i & 15) << 2;
    int nn = n0 - 4 + r;
    s16x4 val = {0, 0, 0, 0};
    if (nn >= 0 && nn < N_TOK) val = *(const s16x4*)(vb + (nn << 6) + c);
    *(s16x4*)(v_s + (i << 2)) = val;
  }

  const float* ag = attn + ((size_t)bh << 12) + lane;
  float col[64];
#pragma unroll
  for (int dd = 0; dd < 64; ++dd) col[dd] = ag[dd << 6];

  float mq = means[0];
  float wc[9];
#pragma unroll
  for (int j = 0; j < 9; ++j) wc[j] = wd[h * 9 + j];
  __syncthreads();

  const short* qb = q + ((size_t)bh << 16);
  for (int t = 0; t < 32; ++t) {
    int ln = (wid << 5) + t;
    int n  = n0 + ln;
    float qv = b2f(qb[(n << 6) + lane]);
    unsigned long long qmask = __ballot((qv - mq) > 0.f);
    float acc = 0.f;
#pragma unroll
    for (int dd = 0; dd < 64; ++dd) {
      float bitf = (float)((unsigned)((qmask >> dd) & 1ull));
      acc = fmaf(bitf, col[dd], acc);
    }
    float vv = b2f(v_s[((ln + 4) << 6) + lane]);
    float o = 0.5f * vv + acc * 0.3183098861837907f;
    float ss = o * o;
#pragma unroll
    for (int off = 32; off; off >>= 1) ss += __shfl_xor(ss, off);
    o *= rsqrtf(ss);
#pragma unroll
    for (int j = 0; j < 9; ++j)
      o += wc[j] * b2f(v_s[((ln + j) << 6) + lane]);
    mid[(size_t)((b << 10) | n) * 768 + (h << 6) + lane] = f2b(o);
  }
}

extern "C" void kernel_launch(void* const* d_in, const int* in_sizes, int n_in,
                              void* d_out, int out_size, void* d_ws, size_t ws_size,
                              hipStream_t stream) {
  (void)in_sizes; (void)n_in; (void)out_size; (void)ws_size;
  const float* x       = (const float*)d_in[0];
  const float* w_qkv   = (const float*)d_in[3];
  const float* w_dconv = (const float*)d_in[4];
  const float* w_proj  = (const float*)d_in[5];
  const float* b_proj  = (const float*)d_in[6];

  // ---- workspace layout (phase-safe aliasing), ~130.5 MB ----
  char* ws = (char*)d_ws;
  short* qbuf = (short*)ws;                         // 3*QKV_E shorts
  short* kbuf = qbuf + QKV_E;
  short* vbuf = kbuf + QKV_E;
  char*  r2   = ws + (size_t)3 * QKV_E * 2;         // 3.54 MB region:
  short* wqkvT    = (short*)r2;                     //   phases 0-1 (3.54 MB)
  float* attn     = (float*)r2;                     //   phases 4-5 (3.15 MB)
  short* mid  = (short*)(r2 + 3538944);             // 25.2 MB, phases 5-6
  float* partials = (float*)mid;                    //   phases 1-2 (6 KB) —
                                                    //   mid unwritten till ph5
  char*  r4   = (char*)mid + (size_t)16384 * 768 * 2;
  short* xb        = (short*)r4;                    // 25.2 MB, phases 0-1
  float* attn_part = (float*)r4;                    //   reused ph 3 (12.6 MB)
  short* wprojT = (short*)(r4 + (size_t)QKV_E * 2); // 1.18 MB, phases 0,6
  float* means  = (float*)((char*)wprojT + (size_t)768 * 768 * 2);

  // 0) convert x -> bf16; transpose+convert weights
  cvt_bf16_kernel<<<QKV_E / 8 / 256, 256, 0, stream>>>(x, xb, QKV_E / 8);
  dim3 gt1(2304 / 64, 768 / 64);
  transpose_cvt_kernel<<<gt1, 256, 0, stream>>>(w_qkv, wqkvT, 768, 2304);
  dim3 gt2(768 / 64, 768 / 64);
  transpose_cvt_kernel<<<gt2, 256, 0, stream>>>(w_proj, wprojT, 768, 768);

  // 1) QKV GEMM (+fused q/k row-norm + mean partials) -> q,k,v [B,h,N,d]
  gemm128<0><<<(2304 / 128) * (16384 / 128), 256, 0, stream>>>(
      xb, wqkvT, 2304, 768, 18, qbuf, nullptr, nullptr, partials);

  // 2) global means of normalized q,k
  mean_reduce_kernel<<<1, 256, 0, stream>>>(partials, means);

  // 3-4) attn = binarized(k)^T v, ballot-broadcast partials + reduce
  attn_part_kernel<<<B_ * HEADS_ * ACH, 256, 0, stream>>>(kbuf, vbuf, means, attn_part);
  attn_reduce_kernel<<<B_ * HEADS_ * 4096 / 256, 256, 0, stream>>>(attn_part, attn);

  // 5) out rows -> mid bf16 [B,N,768]
  out_kernel<<<ROWS_ / 128, 256, 0, stream>>>(qbuf, vbuf, attn, means, w_dconv, mid);

  // 6) projection: mid @ wprojT^T + b_proj -> d_out f32
  gemm128<1><<<(768 / 128) * (16384 / 128), 256, 0, stream>>>(
      mid, wprojT, 768, 768, 6, nullptr, (float*)d_out, b_proj, nullptr);
}